// Round 3
// baseline (203.342 us; speedup 1.0000x reference)
//
#include <hip/hip_runtime.h>
#include <hip/hip_bf16.h>
#include <stdint.h>

#define N_NODES 50000
#define N_EDGES 800000
#define IN_CH   128
#define NEG_SLOPE 0.2f

#define PROJ_BLOCKS 782          // ceil(3125 waves / 4); waves cover 16 rows each
#define E_PER 8                  // legacy fill: edges per thread
#define FILL_BLOCKS 391          // legacy fill: ceil(800000 / (256*8))
#define HIST_WORDS 12500         // 50000 u8 counters packed 4-per-u32 (50 KB LDS)

typedef short short8 __attribute__((ext_vector_type(8)));
typedef float f32x4  __attribute__((ext_vector_type(4)));
typedef float f32x2  __attribute__((ext_vector_type(2)));
typedef int   i32x4  __attribute__((ext_vector_type(4)));

static __device__ __forceinline__ float bf_lo(uint32_t p) { return __uint_as_float(p << 16); }
static __device__ __forceinline__ float bf_hi(uint32_t p) { return __uint_as_float(p & 0xffff0000u); }
static __device__ __forceinline__ uint16_t f_to_bf(float f) {
    uint32_t u = __float_as_uint(f);
    u += 0x7fffu + ((u >> 16) & 1u);   // round-to-nearest-even
    return (uint16_t)(u >> 16);
}
static __device__ __forceinline__ float lrelu(float x) { return fmaxf(x, NEG_SLOPE * x); }

// 16-lane sum-broadcast, pure VALU via DPP butterfly.
static __device__ __forceinline__ float sum16(float x) {
    x += __uint_as_float(__builtin_amdgcn_update_dpp(0, __float_as_uint(x), 0xB1,  0xf, 0xf, true)); // quad_perm[1,0,3,2]
    x += __uint_as_float(__builtin_amdgcn_update_dpp(0, __float_as_uint(x), 0x4E,  0xf, 0xf, true)); // quad_perm[2,3,0,1]
    x += __uint_as_float(__builtin_amdgcn_update_dpp(0, __float_as_uint(x), 0x141, 0xf, 0xf, true)); // row_half_mirror
    x += __uint_as_float(__builtin_amdgcn_update_dpp(0, __float_as_uint(x), 0x140, 0xf, 0xf, true)); // row_mirror
    return x;
}

// ---------------------------------------------------------------------------
// Shared proj body: xl = x@Wl^T+bl (f32, into d_out), xr = x@Wr^T+br (bf16).
// One wave per 16 rows, MFMA 16x16x32 bf16, wswz pre-swizzled B-fragments.
// ---------------------------------------------------------------------------
static __device__ __forceinline__ void proj_body(
    int wave, int lane,
    const float* __restrict__ x, const __hip_bfloat16* __restrict__ wswz,
    const float* __restrict__ bl, const float* __restrict__ br,
    float* __restrict__ xl, __hip_bfloat16* __restrict__ xr)
{
    int rowbase = wave * 16;
    if (rowbase >= N_NODES) return;
    int m = lane & 15;        // A row / B col within tile
    int quad = lane >> 4;     // k-group selector

    short8 afrag[4];
    const float* xrow = x + (size_t)(rowbase + m) * IN_CH;
#pragma unroll
    for (int ch = 0; ch < 4; ++ch) {
        f32x4 p0 = *(const f32x4*)(xrow + ch * 32 + quad * 8);
        f32x4 p1 = *(const f32x4*)(xrow + ch * 32 + quad * 8 + 4);
        short8 f;
#pragma unroll
        for (int j = 0; j < 4; ++j) { f[j] = (short)f_to_bf(p0[j]); f[j + 4] = (short)f_to_bf(p1[j]); }
        afrag[ch] = f;
    }

    const short* wz = (const short*)wswz;
#pragma unroll
    for (int ct = 0; ct < 16; ++ct) {
        const float* bv = (ct < 8) ? bl : br;
        int o = ((ct & 7) << 4) + m;   // output column (0..127)
        f32x4 acc = {0.f, 0.f, 0.f, 0.f};
#pragma unroll
        for (int ch = 0; ch < 4; ++ch) {
            short8 bfrag = *(const short8*)(wz + ((size_t)(ct * 4 + ch) * 64 + lane) * 8);
            acc = __builtin_amdgcn_mfma_f32_16x16x32_bf16(afrag[ch], bfrag, acc, 0, 0, 0);
        }
        float bias_v = bv[o];
        // D layout: row = quad*4 + r, col = m   [m89-verified]
        if (ct < 8) {
#pragma unroll
            for (int r = 0; r < 4; ++r)
                xl[(size_t)(rowbase + quad * 4 + r) * IN_CH + o] = acc[r] + bias_v;
        } else {
#pragma unroll
            for (int r = 0; r < 4; ++r)
                xr[(size_t)(rowbase + quad * 4 + r) * IN_CH + o] = __float2bfloat16(acc[r] + bias_v);
        }
    }
}

// ---------------------------------------------------------------------------
// Weight swizzle body (Wl/Wr f32 -> bf16 MFMA B-fragment order); t < 4096.
// ---------------------------------------------------------------------------
static __device__ __forceinline__ void wswz_body(
    int t, const float* __restrict__ Wl, const float* __restrict__ Wr,
    __hip_bfloat16* __restrict__ wswz)
{
    int ct = t >> 8, rem = t & 255;
    int ch = rem >> 6, lane = rem & 63;
    int m = lane & 15, quad = lane >> 4;
    const float* W = (ct < 8) ? Wl : Wr;
    int o = ((ct & 7) << 4) + m;
    const float* src = W + (size_t)o * IN_CH + ch * 32 + quad * 8;
    short8 f;
#pragma unroll
    for (int j = 0; j < 8; ++j) f[j] = (short)f_to_bf(src[j]);
    *(short8*)((short*)wswz + (size_t)t * 8) = f;
}

// ===========================================================================
// SORT MODE (R3): counting-sort CSR build with ZERO per-edge global atomics.
// R1/R2 falsified L2-line-bounce theories for the 58us fill; remaining model:
// 800k device-scope atomicAdds serialize at memory-side atomic ALUs
// (~6k ops/channel, 16-deep same-address chains).  Replace with block-local
// counting sort: LDS histograms (CU-local atomics) + packed-u8 prefix scan.
// ===========================================================================

// prep_sort: blocks [0,16): wswz swizzle; blocks [16,16+B): per-block LDS
// histogram of tgt over its EPB edges -> H[b] (12500 u32 = 50000 packed u8).
__global__ __launch_bounds__(256) void prep_sort(
    const float* __restrict__ Wl, const float* __restrict__ Wr,
    __hip_bfloat16* __restrict__ wswz,
    const int* __restrict__ ei, uint32_t* __restrict__ H, int EPB)
{
    __shared__ uint32_t hist[HIST_WORDS];
    int tid = threadIdx.x;
    if (blockIdx.x < 16) {
        wswz_body(blockIdx.x * 256 + tid, Wl, Wr, wswz);
        return;
    }
    int fb = blockIdx.x - 16;
    for (int w = tid; w < HIST_WORDS; w += 256) hist[w] = 0;
    __syncthreads();

    const uint32_t* eiw = (const uint32_t*)ei;
    bool z = (eiw[2 * (tid & 63) + 1] == 0u);
    bool is64 = __popcll(__ballot(z)) >= 32;
    int e0 = fb * EPB;
    if (is64) {
        const uint2* e64 = (const uint2*)eiw;
        for (int k = tid; k < EPB; k += 256) {
            int e = e0 + k;
            int s = (int)e64[e].x;
            int t = (int)e64[(size_t)N_EDGES + e].x;
            if ((unsigned)s < N_NODES && (unsigned)t < N_NODES)
                atomicAdd(&hist[t >> 2], 1u << ((t & 3) * 8));
        }
    } else {
        for (int k = tid; k < EPB; k += 256) {
            int e = e0 + k;
            int s = ei[e], t = ei[N_EDGES + e];
            if ((unsigned)s < N_NODES && (unsigned)t < N_NODES)
                atomicAdd(&hist[t >> 2], 1u << ((t & 3) * 8));
        }
    }
    __syncthreads();
    uint32_t* Hb = H + (size_t)fb * HIST_WORDS;
    for (int w = tid; w < HIST_WORDS; w += 256) Hb[w] = hist[w];
}

// proj-only kernel (no 50KB LDS burden, full occupancy).
__global__ __launch_bounds__(256) void proj_kernel(
    const float* __restrict__ x, const __hip_bfloat16* __restrict__ wswz,
    const float* __restrict__ bl, const float* __restrict__ br,
    float* __restrict__ xl, __hip_bfloat16* __restrict__ xr)
{
    proj_body(blockIdx.x * 4 + (threadIdx.x >> 6), threadIdx.x & 63,
              x, wswz, bl, br, xl, xr);
}

// scan: per packed word, exclusive prefix of per-block counts (in place,
// byte-wise: deg <= ~45 so plain u32 adds never carry across bytes).
// Chunked x16 so the loads pipeline instead of a serial latency chain.
__global__ __launch_bounds__(256) void scan_kernel(
    uint32_t* __restrict__ H, int B, uint32_t* __restrict__ degs)
{
    int w = blockIdx.x * 256 + threadIdx.x;
    if (w >= HIST_WORDS) return;
    uint32_t acc = 0;
    for (int c = 0; c < B; c += 16) {
        uint32_t v[16];
#pragma unroll
        for (int j = 0; j < 16; ++j) v[j] = H[(size_t)(c + j) * HIST_WORDS + w];
#pragma unroll
        for (int j = 0; j < 16; ++j) {
            uint32_t t = v[j];
            H[(size_t)(c + j) * HIST_WORDS + w] = acc;
            acc += t;
        }
    }
    degs[w] = acc;   // packed u8 degrees
}

// scatter: block fb loads its base slice into LDS, replays its edges; the
// position comes from the LDS atomic's returned byte -> no global atomics.
// csr slab: u16[64] per node (128B), garbage beyond deg never selected.
__global__ __launch_bounds__(256) void scatter_kernel(
    const int* __restrict__ ei, const uint32_t* __restrict__ H, int EPB,
    uint16_t* __restrict__ csr)
{
    __shared__ uint32_t hist[HIST_WORDS];
    int fb = blockIdx.x, tid = threadIdx.x;
    const uint32_t* Hb = H + (size_t)fb * HIST_WORDS;
    for (int w = tid; w < HIST_WORDS; w += 256) hist[w] = Hb[w];
    __syncthreads();

    const uint32_t* eiw = (const uint32_t*)ei;
    bool z = (eiw[2 * (tid & 63) + 1] == 0u);
    bool is64 = __popcll(__ballot(z)) >= 32;
    int e0 = fb * EPB;
    if (is64) {
        const uint2* e64 = (const uint2*)eiw;
        for (int k = tid; k < EPB; k += 256) {
            int e = e0 + k;
            int s = (int)e64[e].x;
            int t = (int)e64[(size_t)N_EDGES + e].x;
            if ((unsigned)s < N_NODES && (unsigned)t < N_NODES) {
                uint32_t sh = (t & 3) * 8;
                uint32_t old = atomicAdd(&hist[t >> 2], 1u << sh);
                uint32_t pos = (old >> sh) & 255u;
                if (pos < 64u) csr[(size_t)t * 64 + pos] = (uint16_t)s;
            }
        }
    } else {
        for (int k = tid; k < EPB; k += 256) {
            int e = e0 + k;
            int s = ei[e], t = ei[N_EDGES + e];
            if ((unsigned)s < N_NODES && (unsigned)t < N_NODES) {
                uint32_t sh = (t & 3) * 8;
                uint32_t old = atomicAdd(&hist[t >> 2], 1u << sh);
                uint32_t pos = (old >> sh) & 255u;
                if (pos < 64u) csr[(size_t)t * 64 + pos] = (uint16_t)s;
            }
        }
    }
}

// ===========================================================================
// LEGACY MODE (R0 path) — small-workspace fallback.
// ===========================================================================
__global__ __launch_bounds__(256) void prep_legacy(
    const float* __restrict__ Wl, const float* __restrict__ Wr,
    __hip_bfloat16* __restrict__ wswz, int* __restrict__ cnt)
{
    int t = blockIdx.x * 256 + threadIdx.x;   // 64 blocks x 256
    if (t < 4096) wswz_body(t, Wl, Wr, wswz);
    for (int i = t; i < N_NODES; i += 64 * 256) cnt[i] = 0;
}

__global__ __launch_bounds__(256) void mid_legacy(
    const float* __restrict__ x, const __hip_bfloat16* __restrict__ wswz,
    const float* __restrict__ bl, const float* __restrict__ br,
    float* __restrict__ xl, __hip_bfloat16* __restrict__ xr,
    const int* __restrict__ ei, int cap,
    int* __restrict__ cnt, uint16_t* __restrict__ csr)
{
    if (blockIdx.x < PROJ_BLOCKS) {
        proj_body(blockIdx.x * 4 + (threadIdx.x >> 6), threadIdx.x & 63,
                  x, wswz, bl, br, xl, xr);
    } else {
        const uint32_t* eiw = (const uint32_t*)ei;
        bool z = (eiw[2 * (threadIdx.x & 63) + 1] == 0u);
        bool is64 = __popcll(__ballot(z)) >= 32;

        int tid = (blockIdx.x - PROJ_BLOCKS) * 256 + threadIdx.x;
        int e0 = tid * E_PER;
        if (e0 >= N_EDGES) return;

        int src[E_PER], tgt[E_PER];
        if (is64) {
            const int4* ps = (const int4*)(eiw + 2 * (size_t)e0);
            const int4* pt = (const int4*)(eiw + 2 * ((size_t)N_EDGES + e0));
#pragma unroll
            for (int k = 0; k < 4; ++k) {
                int4 s = ps[k], t = pt[k];
                src[2 * k] = s.x; src[2 * k + 1] = s.z;
                tgt[2 * k] = t.x; tgt[2 * k + 1] = t.z;
            }
        } else {
            const int4* ps = (const int4*)(ei + e0);
            const int4* pt = (const int4*)(ei + N_EDGES + e0);
#pragma unroll
            for (int k = 0; k < 2; ++k) {
                int4 s = ps[k], t = pt[k];
                src[4 * k] = s.x; src[4 * k + 1] = s.y; src[4 * k + 2] = s.z; src[4 * k + 3] = s.w;
                tgt[4 * k] = t.x; tgt[4 * k + 1] = t.y; tgt[4 * k + 2] = t.z; tgt[4 * k + 3] = t.w;
            }
        }

        int pos[E_PER];
#pragma unroll
        for (int k = 0; k < E_PER; ++k) {
            bool ok = (unsigned)src[k] < N_NODES && (unsigned)tgt[k] < N_NODES;
            pos[k] = ok ? atomicAdd(&cnt[tgt[k]], 1) : cap;
        }
#pragma unroll
        for (int k = 0; k < E_PER; ++k)
            if (pos[k] < cap) csr[(size_t)tgt[k] * cap + pos[k]] = (uint16_t)src[k];
    }
}

// ---------------------------------------------------------------------------
// Fused attention + aggregation: one wave per target node (unchanged R1
// depth-2 pipeline).  degpacked: 1 -> packed u8 degrees; 0 -> u32 cnt.
// ---------------------------------------------------------------------------
__global__ __launch_bounds__(256) void agg_kernel(
    const __hip_bfloat16* __restrict__ xr,
    const char* __restrict__ degbase, int degpacked,
    const uint16_t* __restrict__ csr, int ldcsr, int cap,
    const float* __restrict__ att, const float* __restrict__ bias,
    float* out /* holds xl on entry */)
{
    int n = blockIdx.x * 4 + (threadIdx.x >> 6);
    if (n >= N_NODES) return;
    int lane = threadIdx.x & 63;

    const uint32_t* xrw = (const uint32_t*)xr;   // 64 dwords per node row

    f32x2 qv = *(const f32x2*)(out + (size_t)n * IN_CH + 2 * lane);
    f32x2 av = *(const f32x2*)(att + 2 * lane);
    f32x2 bv = *(const f32x2*)(bias + 2 * lane);

    int deg;
    if (degpacked) {
        uint32_t pk = ((const uint32_t*)degbase)[n >> 2];
        deg = (int)((pk >> ((n & 3) * 8)) & 255u);
    } else {
        deg = *(const int*)(degbase + (size_t)n * 4);
    }
    deg = min(deg, cap);

    const uint16_t* lst = csr + (size_t)n * ldcsr;
    int idxreg = (int)lst[min(lane, cap - 1)];   // lanes >= deg hold garbage, never selected

    // self-loop
    uint32_t u = xrw[(size_t)n * 64 + lane];
    float v0 = bf_lo(u), v1 = bf_hi(u);
    float t = sum16(lrelu(qv[0] + v0) * av[0] + lrelu(qv[1] + v1) * av[1]);
    float w = __expf(t);
    float lsum = w;
    float acc0 = w * v0, acc1 = w * v1;

    if (deg > 0) {
        int dm1 = deg - 1;
        int s0a = __builtin_amdgcn_readlane(idxreg, 0);
        int s0b = __builtin_amdgcn_readlane(idxreg, min(1, dm1));
        int s1a = __builtin_amdgcn_readlane(idxreg, min(2, dm1));
        int s1b = __builtin_amdgcn_readlane(idxreg, min(3, dm1));
        uint32_t uA0 = xrw[(size_t)s0a * 64 + lane];
        uint32_t uB0 = xrw[(size_t)s0b * 64 + lane];
        uint32_t uA1 = xrw[(size_t)s1a * 64 + lane];
        uint32_t uB1 = xrw[(size_t)s1b * 64 + lane];
        int i = 0;
        while (i + 1 < deg) {
            int s2a = __builtin_amdgcn_readlane(idxreg, min(i + 4, dm1));
            int s2b = __builtin_amdgcn_readlane(idxreg, min(i + 5, dm1));
            uint32_t uA2 = xrw[(size_t)s2a * 64 + lane];
            uint32_t uB2 = xrw[(size_t)s2b * 64 + lane];

            float a0 = bf_lo(uA0), a1 = bf_hi(uA0);
            float b0 = bf_lo(uB0), b1 = bf_hi(uB0);
            float tA = sum16(lrelu(qv[0] + a0) * av[0] + lrelu(qv[1] + a1) * av[1]);
            float tB = sum16(lrelu(qv[0] + b0) * av[0] + lrelu(qv[1] + b1) * av[1]);
            float wA = __expf(tA), wB = __expf(tB);
            lsum += wA + wB;
            acc0 += wA * a0 + wB * b0;
            acc1 += wA * a1 + wB * b1;

            uA0 = uA1; uB0 = uB1;
            uA1 = uA2; uB1 = uB2;
            i += 2;
        }
        if (i < deg) {   // odd tail: uA0 holds edge i (pipeline invariant)
            float a0 = bf_lo(uA0), a1 = bf_hi(uA0);
            float tA = sum16(lrelu(qv[0] + a0) * av[0] + lrelu(qv[1] + a1) * av[1]);
            float wA = __expf(tA);
            lsum += wA;
            acc0 += wA * a0;
            acc1 += wA * a1;
        }
    }

    float inv = 1.f / lsum;
    f32x2 ov;
    ov[0] = acc0 * inv + bv[0];
    ov[1] = acc1 * inv + bv[1];
    *(f32x2*)(out + (size_t)n * IN_CH + 2 * lane) = ov;
}

extern "C" void kernel_launch(void* const* d_in, const int* in_sizes, int n_in,
                              void* d_out, int out_size, void* d_ws, size_t ws_size,
                              hipStream_t stream) {
    const float* x    = (const float*)d_in[0];
    const int*   ei   = (const int*)d_in[1];
    const float* Wl   = (const float*)d_in[2];
    const float* bl   = (const float*)d_in[3];
    const float* Wr   = (const float*)d_in[4];
    const float* br   = (const float*)d_in[5];
    const float* att  = (const float*)d_in[6];
    const float* bias = (const float*)d_in[7];
    float* out = (float*)d_out;

    // workspace layout (bytes):
    //   xr   : [0, 12.8M)                bf16 [N, 128]
    //   wswz : [12.8M, 12.8M+65536)      bf16 [4096*8]
    //   sort mode: H    [AFTER, +B*50000)       per-block packed-u8 hist/base
    //              degs [+50048 pad]            packed u8 degrees
    //              csr  [.., +6.4M)             u16 [N, 64] slabs
    //   legacy:    cnt  [AFTER, +200000) ; csr u16 [N, cap]
    // xl lives in d_out as f32.
    char* ws = (char*)d_ws;
    __hip_bfloat16* xr   = (__hip_bfloat16*)(ws);
    __hip_bfloat16* wswz = (__hip_bfloat16*)(ws + 12800000);
    const size_t AFTER = 12865536;

    int B = 0;
    {
        size_t need64 = AFTER + (size_t)64 * 50000 + 50048 + 6400000;
        size_t need16 = AFTER + (size_t)16 * 50000 + 50048 + 6400000;
        if (ws_size >= need64) B = 64;
        else if (ws_size >= need16) B = 16;
    }

    if (B) {
        uint32_t* H    = (uint32_t*)(ws + AFTER);
        uint32_t* degs = (uint32_t*)(ws + AFTER + (size_t)B * 50000);
        uint16_t* csr  = (uint16_t*)(ws + AFTER + (size_t)B * 50000 + 50048);
        int EPB = N_EDGES / B;

        prep_sort<<<16 + B, 256, 0, stream>>>(Wl, Wr, wswz, ei, H, EPB);
        proj_kernel<<<PROJ_BLOCKS, 256, 0, stream>>>(x, wswz, bl, br, out, xr);
        scan_kernel<<<49, 256, 0, stream>>>(H, B, degs);
        scatter_kernel<<<B, 256, 0, stream>>>(ei, H, EPB, csr);
        agg_kernel<<<N_NODES / 4, 256, 0, stream>>>(
            xr, (const char*)degs, 1, csr, 64, 64, att, bias, out);
    } else {
        int* cnt      = (int*)(ws + AFTER);
        uint16_t* csr = (uint16_t*)(ws + AFTER + 200000);
        long long avail = (ws_size > AFTER + 200000)
                        ? (long long)(ws_size - AFTER - 200000) : 0;
        int cap = (int)(avail / ((long long)N_NODES * 2));
        if (cap > 64) cap = 64;
        if (cap < 1)  cap = 1;

        prep_legacy<<<64, 256, 0, stream>>>(Wl, Wr, wswz, cnt);
        mid_legacy<<<PROJ_BLOCKS + FILL_BLOCKS, 256, 0, stream>>>(
            x, wswz, bl, br, out, xr, ei, cap, cnt, csr);
        agg_kernel<<<N_NODES / 4, 256, 0, stream>>>(
            xr, (const char*)cnt, 0, csr, cap, cap, att, bias, out);
    }
}

// Round 4
// 190.902 us; speedup vs baseline: 1.0652x; 1.0652x over previous
//
#include <hip/hip_runtime.h>
#include <hip/hip_bf16.h>
#include <stdint.h>

#define N_NODES 50000
#define N_EDGES 800000
#define IN_CH   128
#define NEG_SLOPE 0.2f

#define E_PER 8                  // fill: edges per thread (ILP on the atomic chain)
#define FILL_BLOCKS 391          // ceil(800000 / (256*8))

typedef short short8 __attribute__((ext_vector_type(8)));
typedef float f32x4  __attribute__((ext_vector_type(4)));
typedef float f32x2  __attribute__((ext_vector_type(2)));

static __device__ __forceinline__ float bf_lo(uint32_t p) { return __uint_as_float(p << 16); }
static __device__ __forceinline__ float bf_hi(uint32_t p) { return __uint_as_float(p & 0xffff0000u); }
static __device__ __forceinline__ uint16_t f_to_bf(float f) {
    uint32_t u = __float_as_uint(f);
    u += 0x7fffu + ((u >> 16) & 1u);   // round-to-nearest-even
    return (uint16_t)(u >> 16);
}

// leaky-relu on a packed pair: v_pk_mul_f32 + 2x v_max_f32 (no pk_max on CDNA)
static __device__ __forceinline__ f32x2 lrelu2(f32x2 x) {
    f32x2 s = x * NEG_SLOPE;          // v_pk_mul_f32
    f32x2 r;
    r[0] = fmaxf(x[0], s[0]);
    r[1] = fmaxf(x[1], s[1]);
    return r;
}

// 16-lane sum-broadcast via DPP butterfly (builtin form: compiler inserts
// any required hazard nops).  Used for self-loop / odd tail only.
static __device__ __forceinline__ float sum16(float x) {
    x += __uint_as_float(__builtin_amdgcn_update_dpp(0, __float_as_uint(x), 0xB1,  0xf, 0xf, true)); // quad_perm[1,0,3,2]
    x += __uint_as_float(__builtin_amdgcn_update_dpp(0, __float_as_uint(x), 0x4E,  0xf, 0xf, true)); // quad_perm[2,3,0,1]
    x += __uint_as_float(__builtin_amdgcn_update_dpp(0, __float_as_uint(x), 0x141, 0xf, 0xf, true)); // row_half_mirror
    x += __uint_as_float(__builtin_amdgcn_update_dpp(0, __float_as_uint(x), 0x140, 0xf, 0xf, true)); // row_mirror
    return x;
}

// Dual 16-lane sum-broadcast: 8 v_add_f32 DPP instrs, interleaved a/b so each
// DPP reads a register written >=2 instructions earlier (the gfx9-lineage
// "VALU write -> DPP src read" hazard needs 1 slot; interleave provides it
// with zero s_nop padding).  Leading s_nop 0 covers the asm-boundary hazard
// on %0 (written by the immediately preceding compiler VALU add).
static __device__ __forceinline__ void sum16x2(float& a, float& b) {
    asm("s_nop 0\n\t"
        "v_add_f32 %0, %0, %0 quad_perm:[1,0,3,2] row_mask:0xf bank_mask:0xf bound_ctrl:0\n\t"
        "v_add_f32 %1, %1, %1 quad_perm:[1,0,3,2] row_mask:0xf bank_mask:0xf bound_ctrl:0\n\t"
        "v_add_f32 %0, %0, %0 quad_perm:[2,3,0,1] row_mask:0xf bank_mask:0xf bound_ctrl:0\n\t"
        "v_add_f32 %1, %1, %1 quad_perm:[2,3,0,1] row_mask:0xf bank_mask:0xf bound_ctrl:0\n\t"
        "v_add_f32 %0, %0, %0 row_half_mirror row_mask:0xf bank_mask:0xf bound_ctrl:0\n\t"
        "v_add_f32 %1, %1, %1 row_half_mirror row_mask:0xf bank_mask:0xf bound_ctrl:0\n\t"
        "v_add_f32 %0, %0, %0 row_mirror row_mask:0xf bank_mask:0xf bound_ctrl:0\n\t"
        "v_add_f32 %1, %1, %1 row_mirror row_mask:0xf bank_mask:0xf bound_ctrl:0"
        : "+v"(a), "+v"(b));
}

// ---------------------------------------------------------------------------
// prep: (a) swizzle Wl/Wr (f32) -> bf16 in MFMA B-fragment order;
//       (b) zero the cnt array (grid-stride).  One dispatch.
// ---------------------------------------------------------------------------
__global__ __launch_bounds__(256) void prep_kernel(
    const float* __restrict__ Wl, const float* __restrict__ Wr,
    __hip_bfloat16* __restrict__ wswz, int* __restrict__ cnt)
{
    int t = blockIdx.x * 256 + threadIdx.x;   // 64 blocks x 256 = 16384
    if (t < 4096) {
        int ct = t >> 8, rem = t & 255;
        int ch = rem >> 6, lane = rem & 63;
        int m = lane & 15, quad = lane >> 4;
        const float* W = (ct < 8) ? Wl : Wr;
        int o = ((ct & 7) << 4) + m;
        const float* src = W + (size_t)o * IN_CH + ch * 32 + quad * 8;
        short8 f;
#pragma unroll
        for (int j = 0; j < 8; ++j) f[j] = (short)f_to_bf(src[j]);
        *(short8*)((short*)wswz + (size_t)t * 8) = f;
    }
    for (int i = t; i < N_NODES; i += 64 * 256) cnt[i] = 0;
}

// ---------------------------------------------------------------------------
// fill: bucket-CSR build, 8 edges/thread — STANDALONE dispatch this round so
// its isolated dur_us + WRITE_SIZE discriminate the partial-line-write-poison
// theory (ideal write ~1.8MB; poison predicts 40-55MB).
// ---------------------------------------------------------------------------
__global__ __launch_bounds__(256) void fill_kernel(
    const int* __restrict__ ei, int cap,
    int* __restrict__ cnt, uint16_t* __restrict__ csr)
{
    const uint32_t* eiw = (const uint32_t*)ei;
    bool z = (eiw[2 * (threadIdx.x & 63) + 1] == 0u);
    bool is64 = __popcll(__ballot(z)) >= 32;

    int tid = blockIdx.x * 256 + threadIdx.x;
    int e0 = tid * E_PER;
    if (e0 >= N_EDGES) return;   // 800000 % 8 == 0: no partial batches

    int src[E_PER], tgt[E_PER];
    if (is64) {
        // 8 edges = 16 dwords (low/high interleaved), 64B-aligned
        const int4* ps = (const int4*)(eiw + 2 * (size_t)e0);
        const int4* pt = (const int4*)(eiw + 2 * ((size_t)N_EDGES + e0));
#pragma unroll
        for (int k = 0; k < 4; ++k) {
            int4 s = ps[k], t = pt[k];
            src[2 * k] = s.x; src[2 * k + 1] = s.z;
            tgt[2 * k] = t.x; tgt[2 * k + 1] = t.z;
        }
    } else {
        const int4* ps = (const int4*)(ei + e0);
        const int4* pt = (const int4*)(ei + N_EDGES + e0);
#pragma unroll
        for (int k = 0; k < 2; ++k) {
            int4 s = ps[k], t = pt[k];
            src[4 * k] = s.x; src[4 * k + 1] = s.y; src[4 * k + 2] = s.z; src[4 * k + 3] = s.w;
            tgt[4 * k] = t.x; tgt[4 * k + 1] = t.y; tgt[4 * k + 2] = t.z; tgt[4 * k + 3] = t.w;
        }
    }

    int pos[E_PER];
#pragma unroll
    for (int k = 0; k < E_PER; ++k) {
        bool ok = (unsigned)src[k] < N_NODES && (unsigned)tgt[k] < N_NODES;
        pos[k] = ok ? atomicAdd(&cnt[tgt[k]], 1) : cap;   // cap => dropped below
    }
#pragma unroll
    for (int k = 0; k < E_PER; ++k)
        if (pos[k] < cap) csr[(size_t)tgt[k] * cap + pos[k]] = (uint16_t)src[k];
}

// ---------------------------------------------------------------------------
// proj: xl = x@Wl^T+bl (f32 -> d_out), xr = x@Wr^T+br (bf16).
// R4: 4 waves per block SHARE one 16-row group; wave w computes ct in
// [4w, 4w+4) -> 12500 waves (vs 3125), 4x latency-hiding for the store-heavy
// epilogue that capped mid at ~22% occupancy.  x rows read 4x (L1-hot).
// ---------------------------------------------------------------------------
__global__ __launch_bounds__(256) void proj_kernel(
    const float* __restrict__ x, const __hip_bfloat16* __restrict__ wswz,
    const float* __restrict__ bl, const float* __restrict__ br,
    float* __restrict__ xl, __hip_bfloat16* __restrict__ xr)
{
    int rowbase = blockIdx.x * 16;            // grid = 3125 exactly
    int lane = threadIdx.x & 63;
    int widx = threadIdx.x >> 6;              // 0..3: ct group
    int m = lane & 15;                        // A row / B col within tile
    int quad = lane >> 4;                     // k-group selector

    short8 afrag[4];
    const float* xrow = x + (size_t)(rowbase + m) * IN_CH;
#pragma unroll
    for (int ch = 0; ch < 4; ++ch) {
        f32x4 p0 = *(const f32x4*)(xrow + ch * 32 + quad * 8);
        f32x4 p1 = *(const f32x4*)(xrow + ch * 32 + quad * 8 + 4);
        short8 f;
#pragma unroll
        for (int j = 0; j < 4; ++j) { f[j] = (short)f_to_bf(p0[j]); f[j + 4] = (short)f_to_bf(p1[j]); }
        afrag[ch] = f;
    }

    const short* wz = (const short*)wswz;
    const float* bv = (widx < 2) ? bl : br;   // wave-uniform
#pragma unroll
    for (int cc = 0; cc < 4; ++cc) {
        int ct = widx * 4 + cc;
        int o = ((ct & 7) << 4) + m;          // output column (0..127)
        f32x4 acc = {0.f, 0.f, 0.f, 0.f};
#pragma unroll
        for (int ch = 0; ch < 4; ++ch) {
            short8 bfrag = *(const short8*)(wz + ((size_t)(ct * 4 + ch) * 64 + lane) * 8);
            acc = __builtin_amdgcn_mfma_f32_16x16x32_bf16(afrag[ch], bfrag, acc, 0, 0, 0);
        }
        float bias_v = bv[o];
        // D layout: row = quad*4 + r, col = m   [m89-verified]
        if (widx < 2) {
#pragma unroll
            for (int r = 0; r < 4; ++r)
                xl[(size_t)(rowbase + quad * 4 + r) * IN_CH + o] = acc[r] + bias_v;
        } else {
#pragma unroll
            for (int r = 0; r < 4; ++r)
                xr[(size_t)(rowbase + quad * 4 + r) * IN_CH + o] = __float2bfloat16(acc[r] + bias_v);
        }
    }
}

// ---------------------------------------------------------------------------
// Fused attention + aggregation: one wave per target node.
// R4 VALU cut: packed-f32 pair math (v_pk_add/mul/fma_f32 — each lane's two
// channels are exactly one pack) + dual-edge DPP reduction (sum16x2: 4 DPP
// adds per edge, no mov_dpp, no s_nop padding via a/b interleave).
// Depth-2 software pipeline kept from R1 (4 row loads in flight).
// q read f32 from out (own row), result overwrites it (same wave, RAW-safe).
// ---------------------------------------------------------------------------
__global__ __launch_bounds__(256) void agg_kernel(
    const __hip_bfloat16* __restrict__ xr,
    const int* __restrict__ cnt, const uint16_t* __restrict__ csr, int cap,
    const float* __restrict__ att, const float* __restrict__ bias,
    float* out /* holds xl on entry */)
{
    int n = blockIdx.x * 4 + (threadIdx.x >> 6);
    if (n >= N_NODES) return;
    int lane = threadIdx.x & 63;

    const uint32_t* xrw = (const uint32_t*)xr;   // 64 dwords per node row

    f32x2 qv = *(const f32x2*)(out + (size_t)n * IN_CH + 2 * lane);
    f32x2 av = *(const f32x2*)(att + 2 * lane);
    f32x2 bv = *(const f32x2*)(bias + 2 * lane);

    int deg = min(cnt[n], cap);
    const uint16_t* lst = csr + (size_t)n * cap;
    int idxreg = (int)lst[min(lane, cap - 1)];   // lanes >= deg hold garbage, never selected

    // self-loop
    uint32_t u = xrw[(size_t)n * 64 + lane];
    f32x2 a0v; a0v[0] = bf_lo(u); a0v[1] = bf_hi(u);
    f32x2 p0 = lrelu2(qv + a0v) * av;
    float t = sum16(p0[0] + p0[1]);
    float w = __expf(t);
    float lsum = w;
    f32x2 acc = w * a0v;                          // v_pk_mul_f32

    if (deg > 0) {
        int dm1 = deg - 1;
        int s0a = __builtin_amdgcn_readlane(idxreg, 0);
        int s0b = __builtin_amdgcn_readlane(idxreg, min(1, dm1));
        int s1a = __builtin_amdgcn_readlane(idxreg, min(2, dm1));
        int s1b = __builtin_amdgcn_readlane(idxreg, min(3, dm1));
        uint32_t uA0 = xrw[(size_t)s0a * 64 + lane];
        uint32_t uB0 = xrw[(size_t)s0b * 64 + lane];
        uint32_t uA1 = xrw[(size_t)s1a * 64 + lane];
        uint32_t uB1 = xrw[(size_t)s1b * 64 + lane];
        int i = 0;
        while (i + 1 < deg) {
            int s2a = __builtin_amdgcn_readlane(idxreg, min(i + 4, dm1));
            int s2b = __builtin_amdgcn_readlane(idxreg, min(i + 5, dm1));
            uint32_t uA2 = xrw[(size_t)s2a * 64 + lane];
            uint32_t uB2 = xrw[(size_t)s2b * 64 + lane];

            f32x2 aA; aA[0] = bf_lo(uA0); aA[1] = bf_hi(uA0);
            f32x2 aB; aB[0] = bf_lo(uB0); aB[1] = bf_hi(uB0);
            f32x2 pA = lrelu2(qv + aA) * av;      // pk_add, pk_mul, 2x max, pk_mul
            f32x2 pB = lrelu2(qv + aB) * av;
            float tA = pA[0] + pA[1];
            float tB = pB[0] + pB[1];
            sum16x2(tA, tB);                      // 8 interleaved DPP adds
            float wA = __expf(tA), wB = __expf(tB);
            lsum += wA + wB;
            acc += wA * aA;                       // v_pk_fma_f32
            acc += wB * aB;

            uA0 = uA1; uB0 = uB1;
            uA1 = uA2; uB1 = uB2;
            i += 2;
        }
        if (i < deg) {   // odd tail: uA0 holds edge i (pipeline invariant)
            f32x2 aA; aA[0] = bf_lo(uA0); aA[1] = bf_hi(uA0);
            f32x2 pA = lrelu2(qv + aA) * av;
            float tA = sum16(pA[0] + pA[1]);
            float wA = __expf(tA);
            lsum += wA;
            acc += wA * aA;
        }
    }

    float inv = 1.f / lsum;
    f32x2 ov = acc * inv + bv;                    // pk_mul + pk_add / pk_fma
    *(f32x2*)(out + (size_t)n * IN_CH + 2 * lane) = ov;
}

extern "C" void kernel_launch(void* const* d_in, const int* in_sizes, int n_in,
                              void* d_out, int out_size, void* d_ws, size_t ws_size,
                              hipStream_t stream) {
    const float* x    = (const float*)d_in[0];
    const int*   ei   = (const int*)d_in[1];
    const float* Wl   = (const float*)d_in[2];
    const float* bl   = (const float*)d_in[3];
    const float* Wr   = (const float*)d_in[4];
    const float* br   = (const float*)d_in[5];
    const float* att  = (const float*)d_in[6];
    const float* bias = (const float*)d_in[7];
    float* out = (float*)d_out;

    // workspace layout (bytes):
    //   xr   : [0, 12.8M)                 bf16 [N, 128]
    //   wswz : [12.8M, 12.8M+65536)       bf16 [4096*8]  (swizzled Wl|Wr)
    //   cnt  : [12865536, 13065536)       int  [N]
    //   csr  : [13065536, ...)            u16  [N, cap]
    // xl lives in d_out as f32 (each node's wave reads its own row first).
    const size_t CSR_BASE = 13065536;
    char* ws = (char*)d_ws;
    __hip_bfloat16* xr   = (__hip_bfloat16*)(ws);
    __hip_bfloat16* wswz = (__hip_bfloat16*)(ws + 12800000);
    int*      cnt = (int*)(ws + 12865536);
    uint16_t* csr = (uint16_t*)(ws + CSR_BASE);

    long long avail = (ws_size > CSR_BASE) ? (long long)(ws_size - CSR_BASE) : 0;
    int cap = (int)(avail / ((long long)N_NODES * 2));
    if (cap > 64) cap = 64;
    if (cap < 1)  cap = 1;

    prep_kernel<<<64, 256, 0, stream>>>(Wl, Wr, wswz, cnt);
    fill_kernel<<<FILL_BLOCKS, 256, 0, stream>>>(ei, cap, cnt, csr);
    proj_kernel<<<N_NODES / 16, 256, 0, stream>>>(x, wswz, bl, br, out, xr);
    agg_kernel<<<N_NODES / 4, 256, 0, stream>>>(xr, cnt, csr, cap, att, bias, out);
}

// Round 5
// 177.482 us; speedup vs baseline: 1.1457x; 1.0756x over previous
//
#include <hip/hip_runtime.h>
#include <hip/hip_bf16.h>
#include <stdint.h>

#define N_NODES 50000
#define N_EDGES 800000
#define IN_CH   128
#define NEG_SLOPE 0.2f

// ---- radix CSR build (R5) ----
#define NBUCK   98               // bucket = tgt>>9 (512 nodes per bucket)
#define E1      8000             // edges per pass-1 block
#define FILLB   100              // 800000 / 8000
#define BCAP    12288            // u32 records per bucket region (49152/4)
#define BSTRIDE 49152            // bytes per bucket region == 512*48*2 (csr overlay)
#define CAPR    48               // csr slots per node (Poisson(16): P(deg>48) ~ 1e-12)

// ---- legacy fallback (R4) ----
#define E_PER 8
#define FILL_BLOCKS 391

typedef short short8 __attribute__((ext_vector_type(8)));
typedef float f32x4  __attribute__((ext_vector_type(4)));
typedef float f32x2  __attribute__((ext_vector_type(2)));

static __device__ __forceinline__ float bf_lo(uint32_t p) { return __uint_as_float(p << 16); }
static __device__ __forceinline__ float bf_hi(uint32_t p) { return __uint_as_float(p & 0xffff0000u); }
static __device__ __forceinline__ uint16_t f_to_bf(float f) {
    uint32_t u = __float_as_uint(f);
    u += 0x7fffu + ((u >> 16) & 1u);   // round-to-nearest-even
    return (uint16_t)(u >> 16);
}

// leaky-relu on a packed pair: v_pk_mul_f32 + 2x v_max_f32 (no pk_max on CDNA)
static __device__ __forceinline__ f32x2 lrelu2(f32x2 x) {
    f32x2 s = x * NEG_SLOPE;
    f32x2 r;
    r[0] = fmaxf(x[0], s[0]);
    r[1] = fmaxf(x[1], s[1]);
    return r;
}

// 16-lane sum-broadcast via DPP butterfly (builtin form; self-loop/odd tail).
static __device__ __forceinline__ float sum16(float x) {
    x += __uint_as_float(__builtin_amdgcn_update_dpp(0, __float_as_uint(x), 0xB1,  0xf, 0xf, true)); // quad_perm[1,0,3,2]
    x += __uint_as_float(__builtin_amdgcn_update_dpp(0, __float_as_uint(x), 0x4E,  0xf, 0xf, true)); // quad_perm[2,3,0,1]
    x += __uint_as_float(__builtin_amdgcn_update_dpp(0, __float_as_uint(x), 0x141, 0xf, 0xf, true)); // row_half_mirror
    x += __uint_as_float(__builtin_amdgcn_update_dpp(0, __float_as_uint(x), 0x140, 0xf, 0xf, true)); // row_mirror
    return x;
}

// Dual 16-lane sum-broadcast: 8 interleaved v_add_f32 DPP (R4, verified).
static __device__ __forceinline__ void sum16x2(float& a, float& b) {
    asm("s_nop 0\n\t"
        "v_add_f32 %0, %0, %0 quad_perm:[1,0,3,2] row_mask:0xf bank_mask:0xf bound_ctrl:0\n\t"
        "v_add_f32 %1, %1, %1 quad_perm:[1,0,3,2] row_mask:0xf bank_mask:0xf bound_ctrl:0\n\t"
        "v_add_f32 %0, %0, %0 quad_perm:[2,3,0,1] row_mask:0xf bank_mask:0xf bound_ctrl:0\n\t"
        "v_add_f32 %1, %1, %1 quad_perm:[2,3,0,1] row_mask:0xf bank_mask:0xf bound_ctrl:0\n\t"
        "v_add_f32 %0, %0, %0 row_half_mirror row_mask:0xf bank_mask:0xf bound_ctrl:0\n\t"
        "v_add_f32 %1, %1, %1 row_half_mirror row_mask:0xf bank_mask:0xf bound_ctrl:0\n\t"
        "v_add_f32 %0, %0, %0 row_mirror row_mask:0xf bank_mask:0xf bound_ctrl:0\n\t"
        "v_add_f32 %1, %1, %1 row_mirror row_mask:0xf bank_mask:0xf bound_ctrl:0"
        : "+v"(a), "+v"(b));
}

// ---------------------------------------------------------------------------
// Shared bodies
// ---------------------------------------------------------------------------
static __device__ __forceinline__ void wswz_body(
    int t, const float* __restrict__ Wl, const float* __restrict__ Wr,
    __hip_bfloat16* __restrict__ wswz)
{
    int ct = t >> 8, rem = t & 255;
    int ch = rem >> 6, lane = rem & 63;
    int m = lane & 15, quad = lane >> 4;
    const float* W = (ct < 8) ? Wl : Wr;
    int o = ((ct & 7) << 4) + m;
    const float* src = W + (size_t)o * IN_CH + ch * 32 + quad * 8;
    short8 f;
#pragma unroll
    for (int j = 0; j < 8; ++j) f[j] = (short)f_to_bf(src[j]);
    *(short8*)((short*)wswz + (size_t)t * 8) = f;
}

// proj: 4 waves per block share one 16-row group; wave w does ct in [4w,4w+4)
// (R4 structure, verified).
static __device__ __forceinline__ void proj_body(
    int rowbase, int tid,
    const float* __restrict__ x, const __hip_bfloat16* __restrict__ wswz,
    const float* __restrict__ bl, const float* __restrict__ br,
    float* __restrict__ xl, __hip_bfloat16* __restrict__ xr)
{
    int lane = tid & 63;
    int widx = tid >> 6;              // 0..3: ct group
    int m = lane & 15;
    int quad = lane >> 4;

    short8 afrag[4];
    const float* xrow = x + (size_t)(rowbase + m) * IN_CH;
#pragma unroll
    for (int ch = 0; ch < 4; ++ch) {
        f32x4 p0 = *(const f32x4*)(xrow + ch * 32 + quad * 8);
        f32x4 p1 = *(const f32x4*)(xrow + ch * 32 + quad * 8 + 4);
        short8 f;
#pragma unroll
        for (int j = 0; j < 4; ++j) { f[j] = (short)f_to_bf(p0[j]); f[j + 4] = (short)f_to_bf(p1[j]); }
        afrag[ch] = f;
    }

    const short* wz = (const short*)wswz;
    const float* bv = (widx < 2) ? bl : br;   // wave-uniform
#pragma unroll
    for (int cc = 0; cc < 4; ++cc) {
        int ct = widx * 4 + cc;
        int o = ((ct & 7) << 4) + m;
        f32x4 acc = {0.f, 0.f, 0.f, 0.f};
#pragma unroll
        for (int ch = 0; ch < 4; ++ch) {
            short8 bfrag = *(const short8*)(wz + ((size_t)(ct * 4 + ch) * 64 + lane) * 8);
            acc = __builtin_amdgcn_mfma_f32_16x16x32_bf16(afrag[ch], bfrag, acc, 0, 0, 0);
        }
        float bias_v = bv[o];
        // D layout: row = quad*4 + r, col = m   [m89-verified]
        if (widx < 2) {
#pragma unroll
            for (int r = 0; r < 4; ++r)
                xl[(size_t)(rowbase + quad * 4 + r) * IN_CH + o] = acc[r] + bias_v;
        } else {
#pragma unroll
            for (int r = 0; r < 4; ++r)
                xr[(size_t)(rowbase + quad * 4 + r) * IN_CH + o] = __float2bfloat16(acc[r] + bias_v);
        }
    }
}

// ---------------------------------------------------------------------------
// prep: wswz swizzle + zero zn ints at z (bucket counters OR legacy cnt).
// ---------------------------------------------------------------------------
__global__ __launch_bounds__(256) void prep_kernel(
    const float* __restrict__ Wl, const float* __restrict__ Wr,
    __hip_bfloat16* __restrict__ wswz, int* __restrict__ z, int zn)
{
    int t = blockIdx.x * 256 + threadIdx.x;
    if (t < 4096) wswz_body(t, Wl, Wr, wswz);
    for (int i = t; i < zn; i += 64 * 256) z[i] = 0;
}

// ---------------------------------------------------------------------------
// R5 K1: fused proj + pass-1 binning.
//   blocks [0, FILLB):       LDS counting-sort of 8000 edges by tgt>>9, then
//                            coalesced segment writes to bucket regions.
//                            98 global atomics per block (space reservation),
//                            ZERO per-edge global atomics / scattered stores.
//   blocks [FILLB, +3125):   proj (R4 body).
// ---------------------------------------------------------------------------
__global__ __launch_bounds__(256) void proj_fill(
    const float* __restrict__ x, const __hip_bfloat16* __restrict__ wswz,
    const float* __restrict__ bl, const float* __restrict__ br,
    float* __restrict__ xl, __hip_bfloat16* __restrict__ xr,
    const int* __restrict__ ei, uint32_t* __restrict__ bcnt,
    char* __restrict__ region)
{
    __shared__ uint32_t s_sorted[E1];                 // 32 KB
    __shared__ uint32_t s_hist[NBUCK], s_lstart[NBUCK], s_loc[NBUCK], s_gbase[NBUCK];
    __shared__ uint32_t s_T;

    if (blockIdx.x >= FILLB) {
        proj_body((blockIdx.x - FILLB) * 16, threadIdx.x, x, wswz, bl, br, xl, xr);
        return;
    }

    int tid = threadIdx.x;
    int fb = blockIdx.x;
    for (int i = tid; i < NBUCK; i += 256) s_hist[i] = 0;
    __syncthreads();

    const uint32_t* eiw = (const uint32_t*)ei;
    bool zlo = (eiw[2 * (tid & 63) + 1] == 0u);
    bool is64 = __popcll(__ballot(zlo)) >= 32;
    int e0 = fb * E1;

    // pass A: histogram (LDS atomics only)
    for (int k = tid; k < E1; k += 256) {
        int e = e0 + k;
        int s = is64 ? (int)eiw[2 * (size_t)e] : ei[e];
        int t = is64 ? (int)eiw[2 * ((size_t)N_EDGES + e)] : ei[N_EDGES + e];
        if ((unsigned)s < N_NODES && (unsigned)t < N_NODES)
            atomicAdd(&s_hist[t >> 9], 1u);
    }
    __syncthreads();

    if (tid < NBUCK) s_gbase[tid] = atomicAdd(&bcnt[tid], s_hist[tid]);  // 98 global atomics
    if (tid == 0) {
        uint32_t acc = 0;
        for (int i = 0; i < NBUCK; ++i) { s_lstart[i] = acc; acc += s_hist[i]; }
        s_T = acc;
    }
    __syncthreads();
    if (tid < NBUCK) s_loc[tid] = s_lstart[tid];
    __syncthreads();

    // pass B: scatter into LDS, sorted by bucket (record = tgt<<16 | src)
    for (int k = tid; k < E1; k += 256) {
        int e = e0 + k;
        int s = is64 ? (int)eiw[2 * (size_t)e] : ei[e];
        int t = is64 ? (int)eiw[2 * ((size_t)N_EDGES + e)] : ei[N_EDGES + e];
        if ((unsigned)s < N_NODES && (unsigned)t < N_NODES) {
            uint32_t r = atomicAdd(&s_loc[t >> 9], 1u);
            s_sorted[r] = ((uint32_t)t << 16) | (uint32_t)s;
        }
    }
    __syncthreads();

    // pass C: stream out, per-bucket contiguous segments (coalesced)
    int T = (int)s_T;
    for (int k = tid; k < T; k += 256) {
        uint32_t v = s_sorted[k];
        uint32_t key = v >> 25;                        // tgt>>9
        uint32_t g = s_gbase[key] + (uint32_t)k - s_lstart[key];
        if (g < BCAP)
            ((uint32_t*)(region + (size_t)key * BSTRIDE))[g] = v;
    }
}

// ---------------------------------------------------------------------------
// R5 K2: per-bucket CSR build.  Block b: read bucket b (coalesced), build the
// 512-node CSR in LDS (LDS atomics), overwrite the SAME region with the slab
// (full-line coalesced writes; bin and csr regions are exactly overlaid:
// node n's slab lands at region + 96*n).  Pack degrees as u8.
// ---------------------------------------------------------------------------
__global__ __launch_bounds__(256) void csr_build(
    const uint32_t* __restrict__ bcnt, char* __restrict__ region,
    uint32_t* __restrict__ degs32)
{
    __shared__ uint16_t slab[512 * CAPR];   // 49152 B
    __shared__ uint32_t lcnt[512];
    int b = blockIdx.x, tid = threadIdx.x;
    for (int i = tid; i < 512; i += 256) lcnt[i] = 0;
    __syncthreads();

    uint32_t* reg = (uint32_t*)(region + (size_t)b * BSTRIDE);
    int M = min((int)bcnt[b], BCAP);
    for (int k = tid; k < M; k += 256) {
        uint32_t v = reg[k];
        int node = (int)((v >> 16) & 511u);
        uint32_t pos = atomicAdd(&lcnt[node], 1u);
        if (pos < CAPR) slab[node * CAPR + pos] = (uint16_t)(v & 0xffffu);
    }
    __syncthreads();

    // slab -> global (overlay; all of reg was read before this barrier)
    const uint32_t* sw = (const uint32_t*)slab;
    for (int j = tid; j < (512 * CAPR / 2); j += 256) reg[j] = sw[j];
    if (tid < 128) {
        uint32_t p = 0;
#pragma unroll
        for (int q = 0; q < 4; ++q) {
            uint32_t d = min(lcnt[tid * 4 + q], (uint32_t)CAPR);
            p |= d << (q * 8);
        }
        degs32[b * 128 + tid] = p;
    }
}

// ---------------------------------------------------------------------------
// Legacy fill (R4): bucket-CSR via per-edge global atomics (fallback only).
// ---------------------------------------------------------------------------
__global__ __launch_bounds__(256) void fill_kernel(
    const int* __restrict__ ei, int cap,
    int* __restrict__ cnt, uint16_t* __restrict__ csr)
{
    const uint32_t* eiw = (const uint32_t*)ei;
    bool z = (eiw[2 * (threadIdx.x & 63) + 1] == 0u);
    bool is64 = __popcll(__ballot(z)) >= 32;

    int tid = blockIdx.x * 256 + threadIdx.x;
    int e0 = tid * E_PER;
    if (e0 >= N_EDGES) return;

    int src[E_PER], tgt[E_PER];
    if (is64) {
        const int4* ps = (const int4*)(eiw + 2 * (size_t)e0);
        const int4* pt = (const int4*)(eiw + 2 * ((size_t)N_EDGES + e0));
#pragma unroll
        for (int k = 0; k < 4; ++k) {
            int4 s = ps[k], t = pt[k];
            src[2 * k] = s.x; src[2 * k + 1] = s.z;
            tgt[2 * k] = t.x; tgt[2 * k + 1] = t.z;
        }
    } else {
        const int4* ps = (const int4*)(ei + e0);
        const int4* pt = (const int4*)(ei + N_EDGES + e0);
#pragma unroll
        for (int k = 0; k < 2; ++k) {
            int4 s = ps[k], t = pt[k];
            src[4 * k] = s.x; src[4 * k + 1] = s.y; src[4 * k + 2] = s.z; src[4 * k + 3] = s.w;
            tgt[4 * k] = t.x; tgt[4 * k + 1] = t.y; tgt[4 * k + 2] = t.z; tgt[4 * k + 3] = t.w;
        }
    }

    int pos[E_PER];
#pragma unroll
    for (int k = 0; k < E_PER; ++k) {
        bool ok = (unsigned)src[k] < N_NODES && (unsigned)tgt[k] < N_NODES;
        pos[k] = ok ? atomicAdd(&cnt[tgt[k]], 1) : cap;
    }
#pragma unroll
    for (int k = 0; k < E_PER; ++k)
        if (pos[k] < cap) csr[(size_t)tgt[k] * cap + pos[k]] = (uint16_t)src[k];
}

// Legacy standalone proj.
__global__ __launch_bounds__(256) void proj_kernel(
    const float* __restrict__ x, const __hip_bfloat16* __restrict__ wswz,
    const float* __restrict__ bl, const float* __restrict__ br,
    float* __restrict__ xl, __hip_bfloat16* __restrict__ xr)
{
    proj_body(blockIdx.x * 16, threadIdx.x, x, wswz, bl, br, xl, xr);
}

// ---------------------------------------------------------------------------
// Fused attention + aggregation (R4 math: pk-f32 pairs + sum16x2 DPP; depth-2
// software pipeline).  degpacked: 1 -> u8 degrees; 0 -> u32 cnt.
// q read f32 from out (own row), result overwrites it (same wave, RAW-safe).
// ---------------------------------------------------------------------------
__global__ __launch_bounds__(256) void agg_kernel(
    const __hip_bfloat16* __restrict__ xr,
    const char* __restrict__ degbase, int degpacked,
    const uint16_t* __restrict__ csr, int ldcsr, int cap,
    const float* __restrict__ att, const float* __restrict__ bias,
    float* out /* holds xl on entry */)
{
    int n = blockIdx.x * 4 + (threadIdx.x >> 6);
    if (n >= N_NODES) return;
    int lane = threadIdx.x & 63;

    const uint32_t* xrw = (const uint32_t*)xr;   // 64 dwords per node row

    f32x2 qv = *(const f32x2*)(out + (size_t)n * IN_CH + 2 * lane);
    f32x2 av = *(const f32x2*)(att + 2 * lane);
    f32x2 bv = *(const f32x2*)(bias + 2 * lane);

    int deg;
    if (degpacked) {
        uint32_t pk = ((const uint32_t*)degbase)[n >> 2];
        deg = (int)((pk >> ((n & 3) * 8)) & 255u);
    } else {
        deg = ((const int*)degbase)[n];
    }
    deg = min(deg, cap);

    const uint16_t* lst = csr + (size_t)n * ldcsr;
    int idxreg = (int)lst[min(lane, cap - 1)];   // lanes >= deg hold garbage, never selected

    // self-loop
    uint32_t u = xrw[(size_t)n * 64 + lane];
    f32x2 a0v; a0v[0] = bf_lo(u); a0v[1] = bf_hi(u);
    f32x2 p0 = lrelu2(qv + a0v) * av;
    float t = sum16(p0[0] + p0[1]);
    float w = __expf(t);
    float lsum = w;
    f32x2 acc = w * a0v;

    if (deg > 0) {
        int dm1 = deg - 1;
        int s0a = __builtin_amdgcn_readlane(idxreg, 0);
        int s0b = __builtin_amdgcn_readlane(idxreg, min(1, dm1));
        int s1a = __builtin_amdgcn_readlane(idxreg, min(2, dm1));
        int s1b = __builtin_amdgcn_readlane(idxreg, min(3, dm1));
        uint32_t uA0 = xrw[(size_t)s0a * 64 + lane];
        uint32_t uB0 = xrw[(size_t)s0b * 64 + lane];
        uint32_t uA1 = xrw[(size_t)s1a * 64 + lane];
        uint32_t uB1 = xrw[(size_t)s1b * 64 + lane];
        int i = 0;
        while (i + 1 < deg) {
            int s2a = __builtin_amdgcn_readlane(idxreg, min(i + 4, dm1));
            int s2b = __builtin_amdgcn_readlane(idxreg, min(i + 5, dm1));
            uint32_t uA2 = xrw[(size_t)s2a * 64 + lane];
            uint32_t uB2 = xrw[(size_t)s2b * 64 + lane];

            f32x2 aA; aA[0] = bf_lo(uA0); aA[1] = bf_hi(uA0);
            f32x2 aB; aB[0] = bf_lo(uB0); aB[1] = bf_hi(uB0);
            f32x2 pA = lrelu2(qv + aA) * av;
            f32x2 pB = lrelu2(qv + aB) * av;
            float tA = pA[0] + pA[1];
            float tB = pB[0] + pB[1];
            sum16x2(tA, tB);
            float wA = __expf(tA), wB = __expf(tB);
            lsum += wA + wB;
            acc += wA * aA;
            acc += wB * aB;

            uA0 = uA1; uB0 = uB1;
            uA1 = uA2; uB1 = uB2;
            i += 2;
        }
        if (i < deg) {
            f32x2 aA; aA[0] = bf_lo(uA0); aA[1] = bf_hi(uA0);
            f32x2 pA = lrelu2(qv + aA) * av;
            float tA = sum16(pA[0] + pA[1]);
            float wA = __expf(tA);
            lsum += wA;
            acc += wA * aA;
        }
    }

    float inv = 1.f / lsum;
    f32x2 ov = acc * inv + bv;
    *(f32x2*)(out + (size_t)n * IN_CH + 2 * lane) = ov;
}

extern "C" void kernel_launch(void* const* d_in, const int* in_sizes, int n_in,
                              void* d_out, int out_size, void* d_ws, size_t ws_size,
                              hipStream_t stream) {
    const float* x    = (const float*)d_in[0];
    const int*   ei   = (const int*)d_in[1];
    const float* Wl   = (const float*)d_in[2];
    const float* bl   = (const float*)d_in[3];
    const float* Wr   = (const float*)d_in[4];
    const float* br   = (const float*)d_in[5];
    const float* att  = (const float*)d_in[6];
    const float* bias = (const float*)d_in[7];
    float* out = (float*)d_out;

    // workspace layout (radix mode, bytes):
    //   xr     : [0, 12.8M)              bf16 [N, 128]
    //   wswz   : [12.8M, +65536)         bf16 [4096*8]
    //   degs   : [12865536, +50176)      u8 [98*512] packed degrees
    //   bcnt   : [12915712, +512)        u32 [98] bucket counters
    //   region : [12916224, +98*49152)   bins (pass1) overlaid with csr slabs
    //                                    (node n's u16[48] slab at +96*n)
    // xl lives in d_out as f32 (each node's wave reads its own row first).
    char* ws = (char*)d_ws;
    __hip_bfloat16* xr   = (__hip_bfloat16*)(ws);
    __hip_bfloat16* wswz = (__hip_bfloat16*)(ws + 12800000);

    const size_t DEGS_OFF = 12865536;
    const size_t BCNT_OFF = 12915712;
    const size_t REG_OFF  = 12916224;
    const size_t NEED     = REG_OFF + (size_t)NBUCK * BSTRIDE;   // 17,733,120

    if (ws_size >= NEED) {
        uint32_t* degs   = (uint32_t*)(ws + DEGS_OFF);
        uint32_t* bcnt   = (uint32_t*)(ws + BCNT_OFF);
        char*     region = ws + REG_OFF;

        prep_kernel<<<64, 256, 0, stream>>>(Wl, Wr, wswz, (int*)bcnt, 128);
        proj_fill<<<FILLB + N_NODES / 16, 256, 0, stream>>>(
            x, wswz, bl, br, out, xr, ei, bcnt, region);
        csr_build<<<NBUCK, 256, 0, stream>>>(bcnt, region, degs);
        agg_kernel<<<N_NODES / 4, 256, 0, stream>>>(
            xr, (const char*)degs, 1, (const uint16_t*)region, CAPR, CAPR,
            att, bias, out);
    } else {
        // legacy (R4) fallback
        const size_t CSR_BASE = 13065536;
        int*      cnt = (int*)(ws + 12865536);
        uint16_t* csr = (uint16_t*)(ws + CSR_BASE);
        long long avail = (ws_size > CSR_BASE) ? (long long)(ws_size - CSR_BASE) : 0;
        int cap = (int)(avail / ((long long)N_NODES * 2));
        if (cap > 64) cap = 64;
        if (cap < 1)  cap = 1;

        prep_kernel<<<64, 256, 0, stream>>>(Wl, Wr, wswz, cnt, N_NODES);
        fill_kernel<<<FILL_BLOCKS, 256, 0, stream>>>(ei, cap, cnt, csr);
        proj_kernel<<<N_NODES / 16, 256, 0, stream>>>(x, wswz, bl, br, out, xr);
        agg_kernel<<<N_NODES / 4, 256, 0, stream>>>(
            xr, (const char*)cnt, 0, csr, cap, cap, att, bias, out);
    }
}

// Round 7
// 164.493 us; speedup vs baseline: 1.2362x; 1.0790x over previous
//
#include <hip/hip_runtime.h>
#include <hip/hip_bf16.h>
#include <stdint.h>

#define N_NODES 50000
#define N_EDGES 800000
#define IN_CH   128
#define NEG_SLOPE 0.2f

// ---- radix CSR build (R6 geometry; R7 fixes the bcnt/region overlap) ----
#define NBUCK   196              // bucket = tgt>>8 (256 nodes per bucket)
#define E1      4000             // edges per pass-1 block (16KB LDS, 8 blocks/CU)
#define FILLB   200              // 800000 / 4000
#define BCAP    6144             // u32 records per bucket region (24576/4)
#define BSTRIDE 24576            // bytes per bucket region == 256*48*2 (csr overlay)
#define CAPR    48               // csr slots per node (Poisson(16): P(deg>48)*N ~ 5e-11)

// ---- legacy fallback (R4) ----
#define E_PER 8
#define FILL_BLOCKS 391

typedef short short8 __attribute__((ext_vector_type(8)));
typedef float f32x4  __attribute__((ext_vector_type(4)));
typedef float f32x2  __attribute__((ext_vector_type(2)));

static __device__ __forceinline__ float bf_lo(uint32_t p) { return __uint_as_float(p << 16); }
static __device__ __forceinline__ float bf_hi(uint32_t p) { return __uint_as_float(p & 0xffff0000u); }
static __device__ __forceinline__ uint16_t f_to_bf(float f) {
    uint32_t u = __float_as_uint(f);
    u += 0x7fffu + ((u >> 16) & 1u);   // round-to-nearest-even
    return (uint16_t)(u >> 16);
}

// leaky-relu on a packed pair: v_pk_mul_f32 + 2x v_max_f32 (no pk_max on CDNA)
static __device__ __forceinline__ f32x2 lrelu2(f32x2 x) {
    f32x2 s = x * NEG_SLOPE;
    f32x2 r;
    r[0] = fmaxf(x[0], s[0]);
    r[1] = fmaxf(x[1], s[1]);
    return r;
}

// 16-lane sum-broadcast via DPP butterfly (builtin form; self-loop/odd tail).
static __device__ __forceinline__ float sum16(float x) {
    x += __uint_as_float(__builtin_amdgcn_update_dpp(0, __float_as_uint(x), 0xB1,  0xf, 0xf, true)); // quad_perm[1,0,3,2]
    x += __uint_as_float(__builtin_amdgcn_update_dpp(0, __float_as_uint(x), 0x4E,  0xf, 0xf, true)); // quad_perm[2,3,0,1]
    x += __uint_as_float(__builtin_amdgcn_update_dpp(0, __float_as_uint(x), 0x141, 0xf, 0xf, true)); // row_half_mirror
    x += __uint_as_float(__builtin_amdgcn_update_dpp(0, __float_as_uint(x), 0x140, 0xf, 0xf, true)); // row_mirror
    return x;
}

// Dual 16-lane sum-broadcast: 8 interleaved v_add_f32 DPP (R4, verified).
static __device__ __forceinline__ void sum16x2(float& a, float& b) {
    asm("s_nop 0\n\t"
        "v_add_f32 %0, %0, %0 quad_perm:[1,0,3,2] row_mask:0xf bank_mask:0xf bound_ctrl:0\n\t"
        "v_add_f32 %1, %1, %1 quad_perm:[1,0,3,2] row_mask:0xf bank_mask:0xf bound_ctrl:0\n\t"
        "v_add_f32 %0, %0, %0 quad_perm:[2,3,0,1] row_mask:0xf bank_mask:0xf bound_ctrl:0\n\t"
        "v_add_f32 %1, %1, %1 quad_perm:[2,3,0,1] row_mask:0xf bank_mask:0xf bound_ctrl:0\n\t"
        "v_add_f32 %0, %0, %0 row_half_mirror row_mask:0xf bank_mask:0xf bound_ctrl:0\n\t"
        "v_add_f32 %1, %1, %1 row_half_mirror row_mask:0xf bank_mask:0xf bound_ctrl:0\n\t"
        "v_add_f32 %0, %0, %0 row_mirror row_mask:0xf bank_mask:0xf bound_ctrl:0\n\t"
        "v_add_f32 %1, %1, %1 row_mirror row_mask:0xf bank_mask:0xf bound_ctrl:0"
        : "+v"(a), "+v"(b));
}

// ---------------------------------------------------------------------------
// Shared bodies
// ---------------------------------------------------------------------------
static __device__ __forceinline__ void wswz_body(
    int t, const float* __restrict__ Wl, const float* __restrict__ Wr,
    __hip_bfloat16* __restrict__ wswz)
{
    int ct = t >> 8, rem = t & 255;
    int ch = rem >> 6, lane = rem & 63;
    int m = lane & 15, quad = lane >> 4;
    const float* W = (ct < 8) ? Wl : Wr;
    int o = ((ct & 7) << 4) + m;
    const float* src = W + (size_t)o * IN_CH + ch * 32 + quad * 8;
    short8 f;
#pragma unroll
    for (int j = 0; j < 8; ++j) f[j] = (short)f_to_bf(src[j]);
    *(short8*)((short*)wswz + (size_t)t * 8) = f;
}

// proj: 4 waves per block share one 16-row group; wave w does ct in [4w,4w+4)
// (R4 structure, verified).
static __device__ __forceinline__ void proj_body(
    int rowbase, int tid,
    const float* __restrict__ x, const __hip_bfloat16* __restrict__ wswz,
    const float* __restrict__ bl, const float* __restrict__ br,
    float* __restrict__ xl, __hip_bfloat16* __restrict__ xr)
{
    int lane = tid & 63;
    int widx = tid >> 6;              // 0..3: ct group
    int m = lane & 15;
    int quad = lane >> 4;

    short8 afrag[4];
    const float* xrow = x + (size_t)(rowbase + m) * IN_CH;
#pragma unroll
    for (int ch = 0; ch < 4; ++ch) {
        f32x4 p0 = *(const f32x4*)(xrow + ch * 32 + quad * 8);
        f32x4 p1 = *(const f32x4*)(xrow + ch * 32 + quad * 8 + 4);
        short8 f;
#pragma unroll
        for (int j = 0; j < 4; ++j) { f[j] = (short)f_to_bf(p0[j]); f[j + 4] = (short)f_to_bf(p1[j]); }
        afrag[ch] = f;
    }

    const short* wz = (const short*)wswz;
    const float* bv = (widx < 2) ? bl : br;   // wave-uniform
#pragma unroll
    for (int cc = 0; cc < 4; ++cc) {
        int ct = widx * 4 + cc;
        int o = ((ct & 7) << 4) + m;
        f32x4 acc = {0.f, 0.f, 0.f, 0.f};
#pragma unroll
        for (int ch = 0; ch < 4; ++ch) {
            short8 bfrag = *(const short8*)(wz + ((size_t)(ct * 4 + ch) * 64 + lane) * 8);
            acc = __builtin_amdgcn_mfma_f32_16x16x32_bf16(afrag[ch], bfrag, acc, 0, 0, 0);
        }
        float bias_v = bv[o];
        // D layout: row = quad*4 + r, col = m   [m89-verified]
        if (widx < 2) {
#pragma unroll
            for (int r = 0; r < 4; ++r)
                xl[(size_t)(rowbase + quad * 4 + r) * IN_CH + o] = acc[r] + bias_v;
        } else {
#pragma unroll
            for (int r = 0; r < 4; ++r)
                xr[(size_t)(rowbase + quad * 4 + r) * IN_CH + o] = __float2bfloat16(acc[r] + bias_v);
        }
    }
}

// ---------------------------------------------------------------------------
// prep: wswz swizzle + zero zn ints at z (bucket counters OR legacy cnt).
// ---------------------------------------------------------------------------
__global__ __launch_bounds__(256) void prep_kernel(
    const float* __restrict__ Wl, const float* __restrict__ Wr,
    __hip_bfloat16* __restrict__ wswz, int* __restrict__ z, int zn)
{
    int t = blockIdx.x * 256 + threadIdx.x;
    if (t < 4096) wswz_body(t, Wl, Wr, wswz);
    for (int i = t; i < zn; i += 64 * 256) z[i] = 0;
}

// ---------------------------------------------------------------------------
// K1: fused proj + pass-1 binning.
//   blocks [0, FILLB):       LDS counting-sort of 4000 edges by tgt>>8, then
//                            coalesced segment writes to bucket regions.
//                            196 global atomics per block (space reservation).
//   blocks [FILLB, +3125):   proj (R4 body).
//   E1=4000 + NBUCK=196 keeps static LDS ~19.5KB so proj blocks run at
//   8 blocks/CU (R5 was 4 at 33.8KB, latency-bound at 23% occupancy).
// ---------------------------------------------------------------------------
__global__ __launch_bounds__(256) void proj_fill(
    const float* __restrict__ x, const __hip_bfloat16* __restrict__ wswz,
    const float* __restrict__ bl, const float* __restrict__ br,
    float* __restrict__ xl, __hip_bfloat16* __restrict__ xr,
    const int* __restrict__ ei, uint32_t* __restrict__ bcnt,
    char* __restrict__ region)
{
    __shared__ uint32_t s_sorted[E1];                 // 16 KB
    __shared__ uint32_t s_hist[NBUCK], s_lstart[NBUCK], s_loc[NBUCK], s_gbase[NBUCK];
    __shared__ uint32_t s_T;

    if (blockIdx.x >= FILLB) {
        proj_body((blockIdx.x - FILLB) * 16, threadIdx.x, x, wswz, bl, br, xl, xr);
        return;
    }

    int tid = threadIdx.x;
    int fb = blockIdx.x;
    for (int i = tid; i < NBUCK; i += 256) s_hist[i] = 0;
    __syncthreads();

    const uint32_t* eiw = (const uint32_t*)ei;
    bool zlo = (eiw[2 * (tid & 63) + 1] == 0u);
    bool is64 = __popcll(__ballot(zlo)) >= 32;
    int e0 = fb * E1;

    // pass A: histogram (LDS atomics only)
    for (int k = tid; k < E1; k += 256) {
        int e = e0 + k;
        int s = is64 ? (int)eiw[2 * (size_t)e] : ei[e];
        int t = is64 ? (int)eiw[2 * ((size_t)N_EDGES + e)] : ei[N_EDGES + e];
        if ((unsigned)s < N_NODES && (unsigned)t < N_NODES)
            atomicAdd(&s_hist[t >> 8], 1u);
    }
    __syncthreads();

    if (tid < NBUCK) s_gbase[tid] = atomicAdd(&bcnt[tid], s_hist[tid]);  // 196 global atomics
    if (tid == 0) {
        uint32_t acc = 0;
        for (int i = 0; i < NBUCK; ++i) { s_lstart[i] = acc; acc += s_hist[i]; }
        s_T = acc;
    }
    __syncthreads();
    if (tid < NBUCK) s_loc[tid] = s_lstart[tid];
    __syncthreads();

    // pass B: scatter into LDS, sorted by bucket (record = tgt<<16 | src)
    for (int k = tid; k < E1; k += 256) {
        int e = e0 + k;
        int s = is64 ? (int)eiw[2 * (size_t)e] : ei[e];
        int t = is64 ? (int)eiw[2 * ((size_t)N_EDGES + e)] : ei[N_EDGES + e];
        if ((unsigned)s < N_NODES && (unsigned)t < N_NODES) {
            uint32_t r = atomicAdd(&s_loc[t >> 8], 1u);
            s_sorted[r] = ((uint32_t)t << 16) | (uint32_t)s;
        }
    }
    __syncthreads();

    // pass C: stream out, per-bucket contiguous segments (coalesced)
    int T = (int)s_T;
    for (int k = tid; k < T; k += 256) {
        uint32_t v = s_sorted[k];
        uint32_t key = v >> 24;                        // tgt>>8
        uint32_t g = s_gbase[key] + (uint32_t)k - s_lstart[key];
        if (g < BCAP)
            ((uint32_t*)(region + (size_t)key * BSTRIDE))[g] = v;
    }
}

// ---------------------------------------------------------------------------
// K2: per-bucket CSR build (196 blocks).  Block b: read bucket b (coalesced),
// build the 256-node CSR in LDS (LDS atomics), overwrite the SAME region with
// the slab (full-line writes; bin and csr regions exactly overlaid: node n's
// u16[48] slab at region + 96*n since 256*96 == BSTRIDE).  Degrees -> u8.
// ---------------------------------------------------------------------------
__global__ __launch_bounds__(256) void csr_build(
    const uint32_t* __restrict__ bcnt, char* __restrict__ region,
    uint32_t* __restrict__ degs32)
{
    __shared__ uint16_t slab[256 * CAPR];   // 24576 B
    __shared__ uint32_t lcnt[256];
    int b = blockIdx.x, tid = threadIdx.x;
    lcnt[tid] = 0;
    __syncthreads();

    uint32_t* reg = (uint32_t*)(region + (size_t)b * BSTRIDE);
    int M = min((int)bcnt[b], BCAP);
    for (int k = tid; k < M; k += 256) {
        uint32_t v = reg[k];
        int node = (int)((v >> 16) & 255u);
        uint32_t pos = atomicAdd(&lcnt[node], 1u);
        if (pos < CAPR) slab[node * CAPR + pos] = (uint16_t)(v & 0xffffu);
    }
    __syncthreads();

    // slab -> global (overlay; all of reg was read before this barrier)
    const uint32_t* sw = (const uint32_t*)slab;
    for (int j = tid; j < (256 * CAPR / 2); j += 256) reg[j] = sw[j];
    if (tid < 64) {
        uint32_t p = 0;
#pragma unroll
        for (int q = 0; q < 4; ++q) {
            uint32_t d = min(lcnt[tid * 4 + q], (uint32_t)CAPR);
            p |= d << (q * 8);
        }
        degs32[b * 64 + tid] = p;
    }
}

// ---------------------------------------------------------------------------
// Legacy fill (R4): bucket-CSR via per-edge global atomics (fallback only).
// ---------------------------------------------------------------------------
__global__ __launch_bounds__(256) void fill_kernel(
    const int* __restrict__ ei, int cap,
    int* __restrict__ cnt, uint16_t* __restrict__ csr)
{
    const uint32_t* eiw = (const uint32_t*)ei;
    bool z = (eiw[2 * (threadIdx.x & 63) + 1] == 0u);
    bool is64 = __popcll(__ballot(z)) >= 32;

    int tid = blockIdx.x * 256 + threadIdx.x;
    int e0 = tid * E_PER;
    if (e0 >= N_EDGES) return;

    int src[E_PER], tgt[E_PER];
    if (is64) {
        const int4* ps = (const int4*)(eiw + 2 * (size_t)e0);
        const int4* pt = (const int4*)(eiw + 2 * ((size_t)N_EDGES + e0));
#pragma unroll
        for (int k = 0; k < 4; ++k) {
            int4 s = ps[k], t = pt[k];
            src[2 * k] = s.x; src[2 * k + 1] = s.z;
            tgt[2 * k] = t.x; tgt[2 * k + 1] = t.z;
        }
    } else {
        const int4* ps = (const int4*)(ei + e0);
        const int4* pt = (const int4*)(ei + N_EDGES + e0);
#pragma unroll
        for (int k = 0; k < 2; ++k) {
            int4 s = ps[k], t = pt[k];
            src[4 * k] = s.x; src[4 * k + 1] = s.y; src[4 * k + 2] = s.z; src[4 * k + 3] = s.w;
            tgt[4 * k] = t.x; tgt[4 * k + 1] = t.y; tgt[4 * k + 2] = t.z; tgt[4 * k + 3] = t.w;
        }
    }

    int pos[E_PER];
#pragma unroll
    for (int k = 0; k < E_PER; ++k) {
        bool ok = (unsigned)src[k] < N_NODES && (unsigned)tgt[k] < N_NODES;
        pos[k] = ok ? atomicAdd(&cnt[tgt[k]], 1) : cap;
    }
#pragma unroll
    for (int k = 0; k < E_PER; ++k)
        if (pos[k] < cap) csr[(size_t)tgt[k] * cap + pos[k]] = (uint16_t)src[k];
}

// Legacy standalone proj.
__global__ __launch_bounds__(256) void proj_kernel(
    const float* __restrict__ x, const __hip_bfloat16* __restrict__ wswz,
    const float* __restrict__ bl, const float* __restrict__ br,
    float* __restrict__ xl, __hip_bfloat16* __restrict__ xr)
{
    proj_body(blockIdx.x * 16, threadIdx.x, x, wswz, bl, br, xl, xr);
}

// ---------------------------------------------------------------------------
// Fused attention + aggregation.  (a) att pre-scaled by log2(e) so the
// per-edge exp is ONE v_exp_f32 (exp(t) == exp2(t*log2e), exact same math);
// (b) depth-3 software pipeline (6 gather loads in flight; VGPR=16 leaves
// huge headroom) to cover L3 gather latency in the ~30% non-VALU stall.
// degpacked: 1 -> u8 degrees; 0 -> u32 cnt.
// q read f32 from out (own row), result overwrites it (same wave, RAW-safe).
// ---------------------------------------------------------------------------
__global__ __launch_bounds__(256) void agg_kernel(
    const __hip_bfloat16* __restrict__ xr,
    const char* __restrict__ degbase, int degpacked,
    const uint16_t* __restrict__ csr, int ldcsr, int cap,
    const float* __restrict__ att, const float* __restrict__ bias,
    float* out /* holds xl on entry */)
{
    int n = blockIdx.x * 4 + (threadIdx.x >> 6);
    if (n >= N_NODES) return;
    int lane = threadIdx.x & 63;

    const uint32_t* xrw = (const uint32_t*)xr;   // 64 dwords per node row

    f32x2 qv = *(const f32x2*)(out + (size_t)n * IN_CH + 2 * lane);
    f32x2 av = *(const f32x2*)(att + 2 * lane);
    av = av * 1.44269504088896f;                 // exp2 prescale (exact: exp(t)=exp2(t*log2e))
    f32x2 bv = *(const f32x2*)(bias + 2 * lane);

    int deg;
    if (degpacked) {
        uint32_t pk = ((const uint32_t*)degbase)[n >> 2];
        deg = (int)((pk >> ((n & 3) * 8)) & 255u);
    } else {
        deg = ((const int*)degbase)[n];
    }
    deg = min(deg, cap);

    const uint16_t* lst = csr + (size_t)n * ldcsr;
    int idxreg = (int)lst[min(lane, cap - 1)];   // lanes >= deg hold garbage, never selected

    // self-loop
    uint32_t u = xrw[(size_t)n * 64 + lane];
    f32x2 a0v; a0v[0] = bf_lo(u); a0v[1] = bf_hi(u);
    f32x2 p0 = lrelu2(qv + a0v) * av;
    float t = sum16(p0[0] + p0[1]);
    float w = __builtin_amdgcn_exp2f(t);
    float lsum = w;
    f32x2 acc = w * a0v;

    if (deg > 0) {
        int dm1 = deg - 1;
        int sA0 = __builtin_amdgcn_readlane(idxreg, 0);
        int sB0 = __builtin_amdgcn_readlane(idxreg, min(1, dm1));
        int sA1 = __builtin_amdgcn_readlane(idxreg, min(2, dm1));
        int sB1 = __builtin_amdgcn_readlane(idxreg, min(3, dm1));
        int sA2 = __builtin_amdgcn_readlane(idxreg, min(4, dm1));
        int sB2 = __builtin_amdgcn_readlane(idxreg, min(5, dm1));
        uint32_t uA0 = xrw[(size_t)sA0 * 64 + lane];
        uint32_t uB0 = xrw[(size_t)sB0 * 64 + lane];
        uint32_t uA1 = xrw[(size_t)sA1 * 64 + lane];
        uint32_t uB1 = xrw[(size_t)sB1 * 64 + lane];
        uint32_t uA2 = xrw[(size_t)sA2 * 64 + lane];
        uint32_t uB2 = xrw[(size_t)sB2 * 64 + lane];
        int i = 0;
        while (i + 1 < deg) {
            int sA3 = __builtin_amdgcn_readlane(idxreg, min(i + 6, dm1));
            int sB3 = __builtin_amdgcn_readlane(idxreg, min(i + 7, dm1));
            uint32_t uA3 = xrw[(size_t)sA3 * 64 + lane];
            uint32_t uB3 = xrw[(size_t)sB3 * 64 + lane];

            f32x2 aA; aA[0] = bf_lo(uA0); aA[1] = bf_hi(uA0);
            f32x2 aB; aB[0] = bf_lo(uB0); aB[1] = bf_hi(uB0);
            f32x2 pA = lrelu2(qv + aA) * av;
            f32x2 pB = lrelu2(qv + aB) * av;
            float tA = pA[0] + pA[1];
            float tB = pB[0] + pB[1];
            sum16x2(tA, tB);
            float wA = __builtin_amdgcn_exp2f(tA), wB = __builtin_amdgcn_exp2f(tB);
            lsum += wA + wB;
            acc += wA * aA;
            acc += wB * aB;

            uA0 = uA1; uB0 = uB1;
            uA1 = uA2; uB1 = uB2;
            uA2 = uA3; uB2 = uB3;
            i += 2;
        }
        if (i < deg) {   // odd tail: uA0 holds edge i (pipeline invariant)
            f32x2 aA; aA[0] = bf_lo(uA0); aA[1] = bf_hi(uA0);
            f32x2 pA = lrelu2(qv + aA) * av;
            float tA = sum16(pA[0] + pA[1]);
            float wA = __builtin_amdgcn_exp2f(tA);
            lsum += wA;
            acc += wA * aA;
        }
    }

    float inv = 1.f / lsum;
    f32x2 ov = acc * inv + bv;
    *(f32x2*)(out + (size_t)n * IN_CH + 2 * lane) = ov;
}

extern "C" void kernel_launch(void* const* d_in, const int* in_sizes, int n_in,
                              void* d_out, int out_size, void* d_ws, size_t ws_size,
                              hipStream_t stream) {
    const float* x    = (const float*)d_in[0];
    const int*   ei   = (const int*)d_in[1];
    const float* Wl   = (const float*)d_in[2];
    const float* bl   = (const float*)d_in[3];
    const float* Wr   = (const float*)d_in[4];
    const float* br   = (const float*)d_in[5];
    const float* att  = (const float*)d_in[6];
    const float* bias = (const float*)d_in[7];
    float* out = (float*)d_out;

    // workspace layout (radix mode, bytes) — R7: region moved past bcnt end
    // (R6 BUG: bcnt grew to 784B and overlapped region by 272B -> corrupted
    //  bucket counters 128..195 and bucket 0's records).
    //   xr     : [0, 12.8M)              bf16 [N, 128]
    //   wswz   : [12.8M, +65536)         bf16 [4096*8]
    //   degs   : [12865536, +50176)      u8 packed degrees (196*64 u32)
    //   bcnt   : [12915712, +784)        u32 [196] bucket counters (ends 12916496)
    //   region : [12916736, +196*24576)  bins (pass1) overlaid with csr slabs
    //                                    (node n's u16[48] slab at +96*n)
    // xl lives in d_out as f32 (each node's wave reads its own row first).
    char* ws = (char*)d_ws;
    __hip_bfloat16* xr   = (__hip_bfloat16*)(ws);
    __hip_bfloat16* wswz = (__hip_bfloat16*)(ws + 12800000);

    const size_t DEGS_OFF = 12865536;
    const size_t BCNT_OFF = 12915712;
    const size_t REG_OFF  = 12916736;    // >= BCNT_OFF + 196*4 = 12916496, 512-aligned
    const size_t NEED     = REG_OFF + (size_t)NBUCK * BSTRIDE;   // 17,733,632

    if (ws_size >= NEED) {
        uint32_t* degs   = (uint32_t*)(ws + DEGS_OFF);
        uint32_t* bcnt   = (uint32_t*)(ws + BCNT_OFF);
        char*     region = ws + REG_OFF;

        prep_kernel<<<64, 256, 0, stream>>>(Wl, Wr, wswz, (int*)bcnt, NBUCK);
        proj_fill<<<FILLB + N_NODES / 16, 256, 0, stream>>>(
            x, wswz, bl, br, out, xr, ei, bcnt, region);
        csr_build<<<NBUCK, 256, 0, stream>>>(bcnt, region, degs);
        agg_kernel<<<N_NODES / 4, 256, 0, stream>>>(
            xr, (const char*)degs, 1, (const uint16_t*)region, CAPR, CAPR,
            att, bias, out);
    } else {
        // legacy (R4) fallback
        const size_t CSR_BASE = 13065536;
        int*      cnt = (int*)(ws + 12865536);
        uint16_t* csr = (uint16_t*)(ws + CSR_BASE);
        long long avail = (ws_size > CSR_BASE) ? (long long)(ws_size - CSR_BASE) : 0;
        int cap = (int)(avail / ((long long)N_NODES * 2));
        if (cap > 64) cap = 64;
        if (cap < 1)  cap = 1;

        prep_kernel<<<64, 256, 0, stream>>>(Wl, Wr, wswz, cnt, N_NODES);
        fill_kernel<<<FILL_BLOCKS, 256, 0, stream>>>(ei, cap, cnt, csr);
        proj_kernel<<<N_NODES / 16, 256, 0, stream>>>(x, wswz, bl, br, out, xr);
        agg_kernel<<<N_NODES / 4, 256, 0, stream>>>(
            xr, (const char*)cnt, 0, csr, cap, cap, att, bias, out);
    }
}

// Round 8
// 162.317 us; speedup vs baseline: 1.2527x; 1.0134x over previous
//
#include <hip/hip_runtime.h>
#include <hip/hip_bf16.h>
#include <stdint.h>

#define N_NODES 50000
#define N_EDGES 800000
#define IN_CH   128
#define NEG_SLOPE 0.2f

// ---- radix CSR build (R7 layout, verified) ----
#define NBUCK   196              // bucket = tgt>>8 (256 nodes per bucket)
#define E1      4000             // edges per pass-1 block (16KB LDS, 8 blocks/CU)
#define FILLB   200              // 800000 / 4000
#define BCAP    6144             // u32 records per bucket region (24576/4)
#define BSTRIDE 24576            // bytes per bucket region == 256*48*2 (csr overlay)
#define CAPR    48               // csr slots per node (Poisson(16): P(deg>48)*N ~ 5e-11)

// ---- legacy fallback (R4) ----
#define E_PER 8
#define FILL_BLOCKS 391

typedef short short8 __attribute__((ext_vector_type(8)));
typedef float f32x4  __attribute__((ext_vector_type(4)));
typedef float f32x2  __attribute__((ext_vector_type(2)));

static __device__ __forceinline__ float bf_lo(uint32_t p) { return __uint_as_float(p << 16); }
static __device__ __forceinline__ float bf_hi(uint32_t p) { return __uint_as_float(p & 0xffff0000u); }
static __device__ __forceinline__ uint16_t f_to_bf(float f) {
    uint32_t u = __float_as_uint(f);
    u += 0x7fffu + ((u >> 16) & 1u);   // round-to-nearest-even
    return (uint16_t)(u >> 16);
}

// leaky-relu on a packed pair: v_pk_mul_f32 + 2x v_max_f32 (no pk_max on CDNA)
static __device__ __forceinline__ f32x2 lrelu2(f32x2 x) {
    f32x2 s = x * NEG_SLOPE;
    f32x2 r;
    r[0] = fmaxf(x[0], s[0]);
    r[1] = fmaxf(x[1], s[1]);
    return r;
}

// single DPP add step (compiler handles hazards for the builtin form)
#define DPPADD(x, ctrl) __uint_as_float(__builtin_amdgcn_update_dpp(0, __float_as_uint(x), ctrl, 0xf, 0xf, true))

// ---------------------------------------------------------------------------
// Shared bodies
// ---------------------------------------------------------------------------
static __device__ __forceinline__ void wswz_body(
    int t, const float* __restrict__ Wl, const float* __restrict__ Wr,
    __hip_bfloat16* __restrict__ wswz)
{
    int ct = t >> 8, rem = t & 255;
    int ch = rem >> 6, lane = rem & 63;
    int m = lane & 15, quad = lane >> 4;
    const float* W = (ct < 8) ? Wl : Wr;
    int o = ((ct & 7) << 4) + m;
    const float* src = W + (size_t)o * IN_CH + ch * 32 + quad * 8;
    short8 f;
#pragma unroll
    for (int j = 0; j < 8; ++j) f[j] = (short)f_to_bf(src[j]);
    *(short8*)((short*)wswz + (size_t)t * 8) = f;
}

// proj: 4 waves per block share one 16-row group; wave w does ct in [4w,4w+4)
static __device__ __forceinline__ void proj_body(
    int rowbase, int tid,
    const float* __restrict__ x, const __hip_bfloat16* __restrict__ wswz,
    const float* __restrict__ bl, const float* __restrict__ br,
    float* __restrict__ xl, __hip_bfloat16* __restrict__ xr)
{
    int lane = tid & 63;
    int widx = tid >> 6;              // 0..3: ct group
    int m = lane & 15;
    int quad = lane >> 4;

    short8 afrag[4];
    const float* xrow = x + (size_t)(rowbase + m) * IN_CH;
#pragma unroll
    for (int ch = 0; ch < 4; ++ch) {
        f32x4 p0 = *(const f32x4*)(xrow + ch * 32 + quad * 8);
        f32x4 p1 = *(const f32x4*)(xrow + ch * 32 + quad * 8 + 4);
        short8 f;
#pragma unroll
        for (int j = 0; j < 4; ++j) { f[j] = (short)f_to_bf(p0[j]); f[j + 4] = (short)f_to_bf(p1[j]); }
        afrag[ch] = f;
    }

    const short* wz = (const short*)wswz;
    const float* bv = (widx < 2) ? bl : br;   // wave-uniform
#pragma unroll
    for (int cc = 0; cc < 4; ++cc) {
        int ct = widx * 4 + cc;
        int o = ((ct & 7) << 4) + m;
        f32x4 acc = {0.f, 0.f, 0.f, 0.f};
#pragma unroll
        for (int ch = 0; ch < 4; ++ch) {
            short8 bfrag = *(const short8*)(wz + ((size_t)(ct * 4 + ch) * 64 + lane) * 8);
            acc = __builtin_amdgcn_mfma_f32_16x16x32_bf16(afrag[ch], bfrag, acc, 0, 0, 0);
        }
        float bias_v = bv[o];
        // D layout: row = quad*4 + r, col = m   [m89-verified]
        if (widx < 2) {
#pragma unroll
            for (int r = 0; r < 4; ++r)
                xl[(size_t)(rowbase + quad * 4 + r) * IN_CH + o] = acc[r] + bias_v;
        } else {
#pragma unroll
            for (int r = 0; r < 4; ++r)
                xr[(size_t)(rowbase + quad * 4 + r) * IN_CH + o] = __float2bfloat16(acc[r] + bias_v);
        }
    }
}

// ---------------------------------------------------------------------------
// prep: wswz swizzle + zero zn ints at z (bucket counters OR legacy cnt).
// ---------------------------------------------------------------------------
__global__ __launch_bounds__(256) void prep_kernel(
    const float* __restrict__ Wl, const float* __restrict__ Wr,
    __hip_bfloat16* __restrict__ wswz, int* __restrict__ z, int zn)
{
    int t = blockIdx.x * 256 + threadIdx.x;
    if (t < 4096) wswz_body(t, Wl, Wr, wswz);
    for (int i = t; i < zn; i += 64 * 256) z[i] = 0;
}

// ---------------------------------------------------------------------------
// K1: fused proj + pass-1 binning (R7, verified).
// ---------------------------------------------------------------------------
__global__ __launch_bounds__(256) void proj_fill(
    const float* __restrict__ x, const __hip_bfloat16* __restrict__ wswz,
    const float* __restrict__ bl, const float* __restrict__ br,
    float* __restrict__ xl, __hip_bfloat16* __restrict__ xr,
    const int* __restrict__ ei, uint32_t* __restrict__ bcnt,
    char* __restrict__ region)
{
    __shared__ uint32_t s_sorted[E1];                 // 16 KB
    __shared__ uint32_t s_hist[NBUCK], s_lstart[NBUCK], s_loc[NBUCK], s_gbase[NBUCK];
    __shared__ uint32_t s_T;

    if (blockIdx.x >= FILLB) {
        proj_body((blockIdx.x - FILLB) * 16, threadIdx.x, x, wswz, bl, br, xl, xr);
        return;
    }

    int tid = threadIdx.x;
    int fb = blockIdx.x;
    for (int i = tid; i < NBUCK; i += 256) s_hist[i] = 0;
    __syncthreads();

    const uint32_t* eiw = (const uint32_t*)ei;
    bool zlo = (eiw[2 * (tid & 63) + 1] == 0u);
    bool is64 = __popcll(__ballot(zlo)) >= 32;
    int e0 = fb * E1;

    // pass A: histogram (LDS atomics only)
    for (int k = tid; k < E1; k += 256) {
        int e = e0 + k;
        int s = is64 ? (int)eiw[2 * (size_t)e] : ei[e];
        int t = is64 ? (int)eiw[2 * ((size_t)N_EDGES + e)] : ei[N_EDGES + e];
        if ((unsigned)s < N_NODES && (unsigned)t < N_NODES)
            atomicAdd(&s_hist[t >> 8], 1u);
    }
    __syncthreads();

    if (tid < NBUCK) s_gbase[tid] = atomicAdd(&bcnt[tid], s_hist[tid]);  // 196 global atomics
    if (tid == 0) {
        uint32_t acc = 0;
        for (int i = 0; i < NBUCK; ++i) { s_lstart[i] = acc; acc += s_hist[i]; }
        s_T = acc;
    }
    __syncthreads();
    if (tid < NBUCK) s_loc[tid] = s_lstart[tid];
    __syncthreads();

    // pass B: scatter into LDS, sorted by bucket (record = tgt<<16 | src)
    for (int k = tid; k < E1; k += 256) {
        int e = e0 + k;
        int s = is64 ? (int)eiw[2 * (size_t)e] : ei[e];
        int t = is64 ? (int)eiw[2 * ((size_t)N_EDGES + e)] : ei[N_EDGES + e];
        if ((unsigned)s < N_NODES && (unsigned)t < N_NODES) {
            uint32_t r = atomicAdd(&s_loc[t >> 8], 1u);
            s_sorted[r] = ((uint32_t)t << 16) | (uint32_t)s;
        }
    }
    __syncthreads();

    // pass C: stream out, per-bucket contiguous segments (coalesced)
    int T = (int)s_T;
    for (int k = tid; k < T; k += 256) {
        uint32_t v = s_sorted[k];
        uint32_t key = v >> 24;                        // tgt>>8
        uint32_t g = s_gbase[key] + (uint32_t)k - s_lstart[key];
        if (g < BCAP)
            ((uint32_t*)(region + (size_t)key * BSTRIDE))[g] = v;
    }
}

// ---------------------------------------------------------------------------
// K2: per-bucket CSR build (R7, verified).
// ---------------------------------------------------------------------------
__global__ __launch_bounds__(256) void csr_build(
    const uint32_t* __restrict__ bcnt, char* __restrict__ region,
    uint32_t* __restrict__ degs32)
{
    __shared__ uint16_t slab[256 * CAPR];   // 24576 B
    __shared__ uint32_t lcnt[256];
    int b = blockIdx.x, tid = threadIdx.x;
    lcnt[tid] = 0;
    __syncthreads();

    uint32_t* reg = (uint32_t*)(region + (size_t)b * BSTRIDE);
    int M = min((int)bcnt[b], BCAP);
    for (int k = tid; k < M; k += 256) {
        uint32_t v = reg[k];
        int node = (int)((v >> 16) & 255u);
        uint32_t pos = atomicAdd(&lcnt[node], 1u);
        if (pos < CAPR) slab[node * CAPR + pos] = (uint16_t)(v & 0xffffu);
    }
    __syncthreads();

    // slab -> global (overlay; all of reg was read before this barrier)
    const uint32_t* sw = (const uint32_t*)slab;
    for (int j = tid; j < (256 * CAPR / 2); j += 256) reg[j] = sw[j];
    if (tid < 64) {
        uint32_t p = 0;
#pragma unroll
        for (int q = 0; q < 4; ++q) {
            uint32_t d = min(lcnt[tid * 4 + q], (uint32_t)CAPR);
            p |= d << (q * 8);
        }
        degs32[b * 64 + tid] = p;
    }
}

// ---------------------------------------------------------------------------
// Legacy fill (R4): bucket-CSR via per-edge global atomics (fallback only).
// ---------------------------------------------------------------------------
__global__ __launch_bounds__(256) void fill_kernel(
    const int* __restrict__ ei, int cap,
    int* __restrict__ cnt, uint16_t* __restrict__ csr)
{
    const uint32_t* eiw = (const uint32_t*)ei;
    bool z = (eiw[2 * (threadIdx.x & 63) + 1] == 0u);
    bool is64 = __popcll(__ballot(z)) >= 32;

    int tid = blockIdx.x * 256 + threadIdx.x;
    int e0 = tid * E_PER;
    if (e0 >= N_EDGES) return;

    int src[E_PER], tgt[E_PER];
    if (is64) {
        const int4* ps = (const int4*)(eiw + 2 * (size_t)e0);
        const int4* pt = (const int4*)(eiw + 2 * ((size_t)N_EDGES + e0));
#pragma unroll
        for (int k = 0; k < 4; ++k) {
            int4 s = ps[k], t = pt[k];
            src[2 * k] = s.x; src[2 * k + 1] = s.z;
            tgt[2 * k] = t.x; tgt[2 * k + 1] = t.z;
        }
    } else {
        const int4* ps = (const int4*)(ei + e0);
        const int4* pt = (const int4*)(ei + N_EDGES + e0);
#pragma unroll
        for (int k = 0; k < 2; ++k) {
            int4 s = ps[k], t = pt[k];
            src[4 * k] = s.x; src[4 * k + 1] = s.y; src[4 * k + 2] = s.z; src[4 * k + 3] = s.w;
            tgt[4 * k] = t.x; tgt[4 * k + 1] = t.y; tgt[4 * k + 2] = t.z; tgt[4 * k + 3] = t.w;
        }
    }

    int pos[E_PER];
#pragma unroll
    for (int k = 0; k < E_PER; ++k) {
        bool ok = (unsigned)src[k] < N_NODES && (unsigned)tgt[k] < N_NODES;
        pos[k] = ok ? atomicAdd(&cnt[tgt[k]], 1) : cap;
    }
#pragma unroll
    for (int k = 0; k < E_PER; ++k)
        if (pos[k] < cap) csr[(size_t)tgt[k] * cap + pos[k]] = (uint16_t)src[k];
}

// Legacy standalone proj.
__global__ __launch_bounds__(256) void proj_kernel(
    const float* __restrict__ x, const __hip_bfloat16* __restrict__ wswz,
    const float* __restrict__ bl, const float* __restrict__ br,
    float* __restrict__ xl, __hip_bfloat16* __restrict__ xr)
{
    proj_body(blockIdx.x * 16, threadIdx.x, x, wswz, bl, br, xl, xr);
}

// ---------------------------------------------------------------------------
// Fused attention + aggregation — R8 re-laning.
// Layout: 32 lanes x 4 channels per ITEM, TWO items per wave
// (lanes 0-31 = item 2p, lanes 32-63 = item 2p+1).  Item 0 = self-loop,
// items 1..deg = neighbors.  Head = 8 lanes (32 ch): score reduce is
// 3 DPP adds (xor1, xor2, half-mirror) and ONE exp2 covers both items
// (vs 8 DPP + 2 exp in the old 64-lane-per-edge layout); one dwordx2
// load serves both items.  Halves combined once at the end via
// __shfl_xor(...,32) (5 values).  Odd item count: single masked tail.
// q read f32 from out (own row), result overwrites it (same wave, RAW-safe).
// ---------------------------------------------------------------------------
__global__ __launch_bounds__(256) void agg_kernel(
    const __hip_bfloat16* __restrict__ xr,
    const char* __restrict__ degbase, int degpacked,
    const uint16_t* __restrict__ csr, int ldcsr, int cap,
    const float* __restrict__ att, const float* __restrict__ bias,
    float* out /* holds xl on entry */)
{
    int n = blockIdx.x * 4 + (threadIdx.x >> 6);
    if (n >= N_NODES) return;
    int lane = threadIdx.x & 63;
    int lpos = lane & 31;
    bool isB = lane >= 32;

    const char* xrb = (const char*)xr;   // 256 B per node row

    f32x4 qv4 = *(const f32x4*)(out + (size_t)n * IN_CH + lpos * 4);
    f32x4 av4 = *(const f32x4*)(att + lpos * 4);
    f32x4 bv4 = *(const f32x4*)(bias + lpos * 4);
    f32x2 q01; q01[0] = qv4[0]; q01[1] = qv4[1];
    f32x2 q23; q23[0] = qv4[2]; q23[1] = qv4[3];
    const float L2E = 1.44269504088896f;      // exp2 prescale (exp(t)=exp2(t*log2e))
    f32x2 a01; a01[0] = av4[0] * L2E; a01[1] = av4[1] * L2E;
    f32x2 a23; a23[0] = av4[2] * L2E; a23[1] = av4[3] * L2E;

    int deg;
    if (degpacked) {
        uint32_t pk = ((const uint32_t*)degbase)[n >> 2];
        deg = (int)((pk >> ((n & 3) * 8)) & 255u);
    } else {
        deg = ((const int*)degbase)[n];
    }
    deg = min(deg, cap);
    deg = min(deg, 63);                  // items = deg+1 <= 64 (readlane bound)

    // item registry: lane k holds item k's node id (k=0 -> self)
    const uint16_t* lst = csr + (size_t)n * ldcsr;
    int idxreg = (int)lst[min(max(lane - 1, 0), cap - 1)];
    idxreg = (lane == 0) ? n : idxreg;

    int last = deg;                      // highest valid item index
    int FP   = (deg + 1) >> 1;           // full pairs
    int ODD  = (deg + 1) & 1;

    float lsum = 0.f;
    f32x2 acc0 = {0.f, 0.f}, acc1 = {0.f, 0.f};

#define PAIR_LOAD(p, udst) { \
        int sa_ = __builtin_amdgcn_readlane(idxreg, min(2 * (p), last)); \
        int sb_ = __builtin_amdgcn_readlane(idxreg, min(2 * (p) + 1, last)); \
        int vs_ = isB ? sb_ : sa_; \
        udst = *(const uint2*)(xrb + (uint32_t)vs_ * 256u + (uint32_t)lpos * 8u); \
    }

#define PAIR_EVAL(u, MASKED) { \
        f32x2 c0_, c1_; \
        c0_[0] = bf_lo((u).x); c0_[1] = bf_hi((u).x); \
        c1_[0] = bf_lo((u).y); c1_[1] = bf_hi((u).y); \
        f32x2 r0_ = lrelu2(q01 + c0_) * a01; \
        f32x2 r1_ = lrelu2(q23 + c1_) * a23; \
        float t_ = (r0_[0] + r0_[1]) + (r1_[0] + r1_[1]); \
        t_ += DPPADD(t_, 0xB1);   /* quad_perm[1,0,3,2]: xor1 */ \
        t_ += DPPADD(t_, 0x4E);   /* quad_perm[2,3,0,1]: xor2 */ \
        t_ += DPPADD(t_, 0x141);  /* row_half_mirror: 8-lane sum done */ \
        float w_ = __builtin_amdgcn_exp2f(t_); \
        if (MASKED) w_ = isB ? 0.f : w_; \
        lsum += w_; \
        acc0 += w_ * c0_; \
        acc1 += w_ * c1_; \
    }

    // depth-2 pipeline over pairs (clamped indices -> extra loads are valid rows)
    uint2 u0, u1;
    PAIR_LOAD(0, u0);
    PAIR_LOAD(1, u1);
    for (int p = 0; p < FP; ++p) {
        uint2 u2;
        PAIR_LOAD(p + 2, u2);
        PAIR_EVAL(u0, false);
        u0 = u1; u1 = u2;
    }
    if (ODD) {
        PAIR_EVAL(u0, true);             // tail item: half B duplicates -> zeroed
    }

    // combine the two wave-halves (disjoint item sets, same channels)
    lsum    += __shfl_xor(lsum,    32);
    acc0[0] += __shfl_xor(acc0[0], 32);
    acc0[1] += __shfl_xor(acc0[1], 32);
    acc1[0] += __shfl_xor(acc1[0], 32);
    acc1[1] += __shfl_xor(acc1[1], 32);

    float inv = 1.f / lsum;
    if (lane < 32) {
        f32x4 ov;
        ov[0] = acc0[0] * inv + bv4[0];
        ov[1] = acc0[1] * inv + bv4[1];
        ov[2] = acc1[0] * inv + bv4[2];
        ov[3] = acc1[1] * inv + bv4[3];
        *(f32x4*)(out + (size_t)n * IN_CH + lpos * 4) = ov;
    }
#undef PAIR_LOAD
#undef PAIR_EVAL
}

extern "C" void kernel_launch(void* const* d_in, const int* in_sizes, int n_in,
                              void* d_out, int out_size, void* d_ws, size_t ws_size,
                              hipStream_t stream) {
    const float* x    = (const float*)d_in[0];
    const int*   ei   = (const int*)d_in[1];
    const float* Wl   = (const float*)d_in[2];
    const float* bl   = (const float*)d_in[3];
    const float* Wr   = (const float*)d_in[4];
    const float* br   = (const float*)d_in[5];
    const float* att  = (const float*)d_in[6];
    const float* bias = (const float*)d_in[7];
    float* out = (float*)d_out;

    // workspace layout (radix mode, bytes):
    //   xr     : [0, 12.8M)              bf16 [N, 128]
    //   wswz   : [12.8M, +65536)         bf16 [4096*8]
    //   degs   : [12865536, +50176)      u8 packed degrees (196*64 u32)
    //   bcnt   : [12915712, +784)        u32 [196] bucket counters (ends 12916496)
    //   region : [12916736, +196*24576)  bins (pass1) overlaid with csr slabs
    //                                    (node n's u16[48] slab at +96*n)
    // xl lives in d_out as f32 (each node's wave reads its own row first).
    char* ws = (char*)d_ws;
    __hip_bfloat16* xr   = (__hip_bfloat16*)(ws);
    __hip_bfloat16* wswz = (__hip_bfloat16*)(ws + 12800000);

    const size_t DEGS_OFF = 12865536;
    const size_t BCNT_OFF = 12915712;
    const size_t REG_OFF  = 12916736;    // >= BCNT_OFF + 196*4 = 12916496, 512-aligned
    const size_t NEED     = REG_OFF + (size_t)NBUCK * BSTRIDE;   // 17,733,632

    if (ws_size >= NEED) {
        uint32_t* degs   = (uint32_t*)(ws + DEGS_OFF);
        uint32_t* bcnt   = (uint32_t*)(ws + BCNT_OFF);
        char*     region = ws + REG_OFF;

        prep_kernel<<<64, 256, 0, stream>>>(Wl, Wr, wswz, (int*)bcnt, NBUCK);
        proj_fill<<<FILLB + N_NODES / 16, 256, 0, stream>>>(
            x, wswz, bl, br, out, xr, ei, bcnt, region);
        csr_build<<<NBUCK, 256, 0, stream>>>(bcnt, region, degs);
        agg_kernel<<<N_NODES / 4, 256, 0, stream>>>(
            xr, (const char*)degs, 1, (const uint16_t*)region, CAPR, CAPR,
            att, bias, out);
    } else {
        // legacy (R4) fallback
        const size_t CSR_BASE = 13065536;
        int*      cnt = (int*)(ws + 12865536);
        uint16_t* csr = (uint16_t*)(ws + CSR_BASE);
        long long avail = (ws_size > CSR_BASE) ? (long long)(ws_size - CSR_BASE) : 0;
        int cap = (int)(avail / ((long long)N_NODES * 2));
        if (cap > 64) cap = 64;
        if (cap < 1)  cap = 1;

        prep_kernel<<<64, 256, 0, stream>>>(Wl, Wr, wswz, cnt, N_NODES);
        fill_kernel<<<FILL_BLOCKS, 256, 0, stream>>>(ei, cap, cnt, csr);
        proj_kernel<<<N_NODES / 16, 256, 0, stream>>>(x, wswz, bl, br, out, xr);
        agg_kernel<<<N_NODES / 4, 256, 0, stream>>>(
            xr, (const char*)cnt, 0, csr, cap, cap, att, bias, out);
    }
}